// Round 2
// baseline (284.694 us; speedup 1.0000x reference)
//
#include <hip/hip_runtime.h>
#include <hip/hip_bf16.h>
#include <stdint.h>

using hbf = __hip_bfloat16;
typedef __bf16 bf16x8 __attribute__((ext_vector_type(8)));
typedef float f32x4 __attribute__((ext_vector_type(4)));

#define MFMA16(a, b, c) __builtin_amdgcn_mfma_f32_16x16x32_bf16((a), (b), (c), 0, 0, 0)

__device__ __forceinline__ void async_copy16(const void* gsrc, void* ldst) {
  __builtin_amdgcn_global_load_lds((const __attribute__((address_space(1))) void*)gsrc,
                                   (__attribute__((address_space(3))) void*)ldst,
                                   16, 0, 0);
}

// ---------------- weight cast + transpose: W[K][N] f32 -> Wt[N][K] bf16 ----------------
__global__ __launch_bounds__(256) void wtrans_kernel(const float* __restrict__ W,
                                                     hbf* __restrict__ Wt,
                                                     int K, int N) {
  __shared__ float tile[64][65];
  const int n0 = blockIdx.x * 64, k0 = blockIdx.y * 64;
  const int tid = threadIdx.x;
#pragma unroll
  for (int i = 0; i < 16; ++i) {
    int idx = tid + i * 256;
    int r = idx >> 6, c = idx & 63;
    tile[r][c] = W[(size_t)(k0 + r) * N + n0 + c];
  }
  __syncthreads();
#pragma unroll
  for (int i = 0; i < 16; ++i) {
    int idx = tid + i * 256;
    int r = idx >> 6, c = idx & 63;
    Wt[(size_t)(n0 + r) * K + k0 + c] = __float2bfloat16(tile[c][r]);
  }
}

// ---------------- LN0: values f32 -> h bf16 ----------------
__global__ __launch_bounds__(64) void ln0_kernel(const float* __restrict__ x,
                                                 const float* __restrict__ g,
                                                 const float* __restrict__ bt,
                                                 hbf* __restrict__ h) {
  const int row = blockIdx.x, l = threadIdx.x;
  const float* xr = x + (size_t)row * 512;
  float v[8], s = 0.f, s2 = 0.f;
#pragma unroll
  for (int i = 0; i < 8; ++i) {
    float t = xr[l + 64 * i];
    v[i] = t; s += t; s2 += t * t;
  }
#pragma unroll
  for (int off = 32; off; off >>= 1) { s += __shfl_xor(s, off); s2 += __shfl_xor(s2, off); }
  float mu = s * (1.f / 512.f);
  float rs = rsqrtf(s2 * (1.f / 512.f) - mu * mu + 1e-3f);
  hbf* hr = h + (size_t)row * 512;
#pragma unroll
  for (int i = 0; i < 8; ++i) {
    int c = l + 64 * i;
    hr[c] = __float2bfloat16((v[i] - mu) * rs * g[c] + bt[c]);
  }
}

// ---------------- residual add + LN1 ----------------
__global__ __launch_bounds__(64) void lnadd_kernel(const float* __restrict__ values,
                                                   const float* __restrict__ obuf,
                                                   const float* __restrict__ g,
                                                   const float* __restrict__ bt,
                                                   float* __restrict__ res1,
                                                   hbf* __restrict__ h2) {
  const int row = blockIdx.x, l = threadIdx.x;
  const float* vr = values + (size_t)row * 512;
  const float* orow = obuf + (size_t)row * 512;
  float* rr = res1 + (size_t)row * 512;
  float v[8], s = 0.f, s2 = 0.f;
#pragma unroll
  for (int i = 0; i < 8; ++i) {
    int c = l + 64 * i;
    float t = vr[c] + orow[c];
    v[i] = t; s += t; s2 += t * t;
    rr[c] = t;
  }
#pragma unroll
  for (int off = 32; off; off >>= 1) { s += __shfl_xor(s, off); s2 += __shfl_xor(s2, off); }
  float mu = s * (1.f / 512.f);
  float rs = rsqrtf(s2 * (1.f / 512.f) - mu * mu + 1e-3f);
  hbf* hr = h2 + (size_t)row * 512;
#pragma unroll
  for (int i = 0; i < 8; ++i) {
    int c = l + 64 * i;
    hr[c] = __float2bfloat16((v[i] - mu) * rs * g[c] + bt[c]);
  }
}

// ---------------- GEMM: A[M][K] bf16 row-major, Bt[N][K] bf16, 128x128 tile ----------------
// EPI 0: out bf16 = relu(acc+bias) ; EPI 1: out bf16 = acc+bias ; EPI 2: out f32 = acc+bias+resid
template <int EPI>
__global__ __launch_bounds__(256) void gemm_bt(const hbf* __restrict__ A,
                                               const hbf* __restrict__ Bt,
                                               const float* __restrict__ bias,
                                               const float* __restrict__ resid,
                                               void* __restrict__ outp,
                                               int M, int N, int K) {
  __shared__ hbf As[128 * 32];
  __shared__ hbf Bs[128 * 32];
  const int tid = threadIdx.x;
  const int lane = tid & 63;
  const int w = tid >> 6;
  const int wm = w >> 1, wn = w & 1;
  const int m0 = blockIdx.y * 128, n0 = blockIdx.x * 128;

  f32x4 acc[4][4] = {};

  int srow[2], scs[2];
#pragma unroll
  for (int p = 0; p < 2; ++p) {
    int off = (w + p * 4) * 1024 + lane * 16;
    int r = off >> 6;
    int slot = (off >> 4) & 3;
    srow[p] = r;
    scs[p] = slot ^ ((r >> 1) & 3);
  }

  for (int kt = 0; kt < K; kt += 32) {
#pragma unroll
    for (int p = 0; p < 2; ++p) {
      const hbf* sa = A + (size_t)(m0 + srow[p]) * K + kt + scs[p] * 8;
      async_copy16(sa, (char*)As + (w + p * 4) * 1024);
      const hbf* sb = Bt + (size_t)(n0 + srow[p]) * K + kt + scs[p] * 8;
      async_copy16(sb, (char*)Bs + (w + p * 4) * 1024);
    }
    __syncthreads();
    bf16x8 af[4], bg[4];
    const int cq = lane >> 4;
#pragma unroll
    for (int i = 0; i < 4; ++i) {
      int m = wm * 64 + i * 16 + (lane & 15);
      int sl = cq ^ ((m >> 1) & 3);
      af[i] = *reinterpret_cast<const bf16x8*>((const char*)As + m * 64 + sl * 16);
      int n = wn * 64 + i * 16 + (lane & 15);
      int sn = cq ^ ((n >> 1) & 3);
      bg[i] = *reinterpret_cast<const bf16x8*>((const char*)Bs + n * 64 + sn * 16);
    }
#pragma unroll
    for (int i = 0; i < 4; ++i)
#pragma unroll
      for (int j = 0; j < 4; ++j)
        acc[i][j] = MFMA16(af[i], bg[j], acc[i][j]);
    __syncthreads();
  }

#pragma unroll
  for (int j = 0; j < 4; ++j) {
    int col = n0 + wn * 64 + j * 16 + (lane & 15);
    float bcol = bias[col];
#pragma unroll
    for (int i = 0; i < 4; ++i) {
      int rowb = m0 + wm * 64 + i * 16 + (lane >> 4) * 4;
#pragma unroll
      for (int r = 0; r < 4; ++r) {
        int row = rowb + r;
        float v = acc[i][j][r] + bcol;
        if (EPI == 0) {
          v = v > 0.f ? v : 0.f;
          ((hbf*)outp)[(size_t)row * N + col] = __float2bfloat16(v);
        } else if (EPI == 1) {
          ((hbf*)outp)[(size_t)row * N + col] = __float2bfloat16(v);
        } else {
          ((float*)outp)[(size_t)row * N + col] = v + resid[(size_t)row * N + col];
        }
      }
    }
  }
}

// ---------------- V transpose: X2 v-slice -> vT[bh][64 d][512 s] bf16 ----------------
__global__ __launch_bounds__(256) void vtrans_kernel(const hbf* __restrict__ X2,
                                                     hbf* __restrict__ vT) {
  __shared__ hbf tile[64][80];
  const int bh = blockIdx.x, s0 = blockIdx.y * 64;
  const int b = bh >> 3, h = bh & 7;
  const int tid = threadIdx.x;
#pragma unroll
  for (int i = 0; i < 2; ++i) {
    int chunk = tid + i * 256;
    int r = chunk >> 3, c8 = (chunk & 7) * 8;
    const hbf* src = X2 + (size_t)(b * 512 + s0 + r) * 1536 + h * 192 + 128 + c8;
    *reinterpret_cast<bf16x8*>(&tile[r][c8]) = *reinterpret_cast<const bf16x8*>(src);
  }
  __syncthreads();
#pragma unroll
  for (int i = 0; i < 2; ++i) {
    int chunk = tid + i * 256;
    int d = chunk >> 3, s8 = (chunk & 7) * 8;
    bf16x8 v;
#pragma unroll
    for (int j = 0; j < 8; ++j) v[j] = *reinterpret_cast<const __bf16*>(&tile[s8 + j][d]);
    *reinterpret_cast<bf16x8*>(vT + ((size_t)bh * 64 + d) * 512 + s0 + s8) = v;
  }
}

// ---------------- relative-position bias: bb[c][bh][q] = q . (Wp[c]+bp)|_h ----------------
__global__ __launch_bounds__(256) void posbias_kernel(const hbf* __restrict__ X2,
                                                      const float* __restrict__ Wp,
                                                      const float* __restrict__ bp,
                                                      float* __restrict__ bb) {
  int idx = blockIdx.x * 256 + threadIdx.x;  // 3*64*512 = 98304
  int c = idx >> 15;
  int r = idx & 32767;
  int bh = r >> 9, q = r & 511;
  int b = bh >> 3, h = bh & 7;
  const hbf* qp = X2 + (size_t)(b * 512 + q) * 1536 + h * 192;
  const float* wr = Wp + c * 512 + h * 64;
  const float* br = bp + h * 64;
  float s = 0.f;
#pragma unroll
  for (int d = 0; d < 64; ++d) s += __bfloat162float(qp[d]) * (wr[d] + br[d]);
  bb[idx] = s;
}

// ---------------- causal flash attention with degenerate relative bias ----------------
__global__ __launch_bounds__(256) void attn_kernel(const hbf* __restrict__ X2,
                                                   const hbf* __restrict__ vT,
                                                   const float* __restrict__ bb,
                                                   float* __restrict__ obuf) {
  __shared__ hbf p_lds[4][16][32];
  const int bh = blockIdx.x;
  const int b = bh >> 3, h = bh & 7;
  const int q0 = blockIdx.y * 64;
  const int tid = threadIdx.x;
  const int lane = tid & 63, w = tid >> 6;
  const int qbase = q0 + w * 16;

  bf16x8 qa[2];
  {
    int qrow = qbase + (lane & 15);
    const hbf* qp = X2 + (size_t)(b * 512 + qrow) * 1536 + h * 192 + (lane >> 4) * 8;
#pragma unroll
    for (int c = 0; c < 2; ++c) qa[c] = *reinterpret_cast<const bf16x8*>(qp + c * 32);
  }
  float bias0[4], bias1[4];
#pragma unroll
  for (int r = 0; r < 4; ++r) {
    int qr = qbase + (lane >> 4) * 4 + r;
    bias0[r] = bb[bh * 512 + qr];
    bias1[r] = bb[32768 + bh * 512 + qr];
  }

  float mrow[4], lsum[4];
  f32x4 oacc[4];
#pragma unroll
  for (int r = 0; r < 4; ++r) { mrow[r] = -1e30f; lsum[r] = 0.f; }
#pragma unroll
  for (int nt = 0; nt < 4; ++nt) oacc[nt] = (f32x4){0.f, 0.f, 0.f, 0.f};

  const int qhi = qbase + 15;
  const int nchunks = (qhi >> 5) + 1;
  for (int ch = 0; ch < nchunks; ++ch) {
    const int k32 = ch * 32;
    f32x4 z = {0.f, 0.f, 0.f, 0.f};
    f32x4 s0, s1;
    {
      const hbf* kp = X2 + (size_t)(b * 512 + k32 + (lane & 15)) * 1536 + h * 192 + 64 + (lane >> 4) * 8;
      bf16x8 kb = *reinterpret_cast<const bf16x8*>(kp);
      s0 = MFMA16(qa[0], kb, z);
      kb = *reinterpret_cast<const bf16x8*>(kp + 32);
      s0 = MFMA16(qa[1], kb, s0);
      const hbf* kp1 = kp + 16 * 1536;
      kb = *reinterpret_cast<const bf16x8*>(kp1);
      s1 = MFMA16(qa[0], kb, z);
      kb = *reinterpret_cast<const bf16x8*>(kp1 + 32);
      s1 = MFMA16(qa[1], kb, s1);
    }
    const int col0 = k32 + (lane & 15);
    const int col1 = col0 + 16;
    float p0[4], p1[4], alpha[4];
#pragma unroll
    for (int r = 0; r < 4; ++r) {
      int q = qbase + (lane >> 4) * 4 + r;
      float sc0 = (col0 > q) ? -1e30f : (s0[r] * 0.125f + (col0 == q ? bias1[r] : bias0[r]));
      float sc1 = (col1 > q) ? -1e30f : (s1[r] * 0.125f + (col1 == q ? bias1[r] : bias0[r]));
      float cm = fmaxf(sc0, sc1);
#pragma unroll
      for (int off = 1; off < 16; off <<= 1) cm = fmaxf(cm, __shfl_xor(cm, off));
      float mn = fmaxf(mrow[r], cm);
      alpha[r] = __expf(mrow[r] - mn);
      mrow[r] = mn;
      float e0 = __expf(sc0 - mn), e1 = __expf(sc1 - mn);
      p0[r] = e0; p1[r] = e1;
      float ps = e0 + e1;
#pragma unroll
      for (int off = 1; off < 16; off <<= 1) ps += __shfl_xor(ps, off);
      lsum[r] = lsum[r] * alpha[r] + ps;
    }
#pragma unroll
    for (int nt = 0; nt < 4; ++nt)
#pragma unroll
      for (int r = 0; r < 4; ++r) oacc[nt][r] *= alpha[r];
#pragma unroll
    for (int r = 0; r < 4; ++r) {
      p_lds[w][(lane >> 4) * 4 + r][lane & 15] = __float2bfloat16(p0[r]);
      p_lds[w][(lane >> 4) * 4 + r][16 + (lane & 15)] = __float2bfloat16(p1[r]);
    }
    bf16x8 pa = *reinterpret_cast<const bf16x8*>(&p_lds[w][lane & 15][(lane >> 4) * 8]);
#pragma unroll
    for (int nt = 0; nt < 4; ++nt) {
      const hbf* vp = vT + ((size_t)bh * 64 + nt * 16 + (lane & 15)) * 512 + k32 + (lane >> 4) * 8;
      bf16x8 vb = *reinterpret_cast<const bf16x8*>(vp);
      oacc[nt] = MFMA16(pa, vb, oacc[nt]);
    }
  }
#pragma unroll
  for (int r = 0; r < 4; ++r) {
    float rl = 1.f / lsum[r];
    int q = qbase + (lane >> 4) * 4 + r;
    float* orow = obuf + (size_t)(b * 512 + q) * 512 + h * 64;
#pragma unroll
    for (int nt = 0; nt < 4; ++nt) orow[nt * 16 + (lane & 15)] = oacc[nt][r] * rl;
  }
}

extern "C" void kernel_launch(void* const* d_in, const int* in_sizes, int n_in,
                              void* d_out, int out_size, void* d_ws, size_t ws_size,
                              hipStream_t stream) {
  const float* values = (const float*)d_in[0];
  const float* ln0_g = (const float*)d_in[2];
  const float* ln0_b = (const float*)d_in[3];
  const float* W0a = (const float*)d_in[4];
  const float* b0a = (const float*)d_in[5];
  const float* W0b = (const float*)d_in[6];
  const float* b0b = (const float*)d_in[7];
  const float* Wp = (const float*)d_in[8];
  const float* bp = (const float*)d_in[9];
  const float* ln1_g = (const float*)d_in[10];
  const float* ln1_b = (const float*)d_in[11];
  const float* W1a = (const float*)d_in[12];
  const float* b1a = (const float*)d_in[13];
  const float* W1b = (const float*)d_in[14];
  const float* b1b = (const float*)d_in[15];

  char* ws = (char*)d_ws;
  hbf* W0a_t = (hbf*)(ws + (0ull << 20));
  hbf* W0b_t = (hbf*)(ws + (2ull << 20));
  hbf* W1a_t = (hbf*)(ws + (8ull << 20));
  hbf* W1b_t = (hbf*)(ws + (10ull << 20));
  hbf* hbuf = (hbf*)(ws + (12ull << 20));   // LN0 out, reused as h2
  hbf* X1 = (hbf*)(ws + (16ull << 20));     // 16MB, reused as X3
  hbf* X2 = (hbf*)(ws + (32ull << 20));     // 12MB (QKV)
  float* obuf = (float*)(ws + (44ull << 20));  // 8MB
  hbf* vT = (hbf*)(ws + (52ull << 20));     // 4MB
  float* bb = (float*)(ws + (56ull << 20)); // 384KB
  float* res1 = (float*)(ws + (57ull << 20));  // 8MB
  hbf* X3 = X1;
  hbf* h2 = hbuf;

  wtrans_kernel<<<dim3(32, 8), 256, 0, stream>>>(W0a, W0a_t, 512, 2048);
  wtrans_kernel<<<dim3(24, 32), 256, 0, stream>>>(W0b, W0b_t, 2048, 1536);
  wtrans_kernel<<<dim3(32, 8), 256, 0, stream>>>(W1a, W1a_t, 512, 2048);
  wtrans_kernel<<<dim3(8, 32), 256, 0, stream>>>(W1b, W1b_t, 2048, 512);

  ln0_kernel<<<4096, 64, 0, stream>>>(values, ln0_g, ln0_b, hbuf);

  gemm_bt<0><<<dim3(16, 32), 256, 0, stream>>>(hbuf, W0a_t, b0a, nullptr, X1, 4096, 2048, 512);
  gemm_bt<1><<<dim3(12, 32), 256, 0, stream>>>(X1, W0b_t, b0b, nullptr, X2, 4096, 1536, 2048);

  vtrans_kernel<<<dim3(64, 8), 256, 0, stream>>>(X2, vT);
  posbias_kernel<<<384, 256, 0, stream>>>(X2, Wp, bp, bb);
  attn_kernel<<<dim3(64, 8), 256, 0, stream>>>(X2, vT, bb, obuf);

  lnadd_kernel<<<4096, 64, 0, stream>>>(values, obuf, ln1_g, ln1_b, res1, h2);

  gemm_bt<0><<<dim3(16, 32), 256, 0, stream>>>(h2, W1a_t, b1a, nullptr, X3, 4096, 2048, 512);
  gemm_bt<2><<<dim3(4, 32), 256, 0, stream>>>(X3, W1b_t, b1b, res1, (float*)d_out, 4096, 512, 2048);
}

// Round 3
// 247.211 us; speedup vs baseline: 1.1516x; 1.1516x over previous
//
#include <hip/hip_runtime.h>
#include <hip/hip_bf16.h>
#include <stdint.h>

using hbf = __hip_bfloat16;
typedef __bf16 bf16x8 __attribute__((ext_vector_type(8)));
typedef float f32x4 __attribute__((ext_vector_type(4)));

#define MFMA16(a, b, c) __builtin_amdgcn_mfma_f32_16x16x32_bf16((a), (b), (c), 0, 0, 0)

__device__ __forceinline__ void async_copy16(const void* gsrc, void* ldst) {
  __builtin_amdgcn_global_load_lds((const __attribute__((address_space(1))) void*)gsrc,
                                   (__attribute__((address_space(3))) void*)ldst,
                                   16, 0, 0);
}

// ---------------- weight cast + transpose: W[K][N] f32 -> Wt[N][K] bf16 ----------------
__global__ __launch_bounds__(256) void wtrans_kernel(const float* __restrict__ W,
                                                     hbf* __restrict__ Wt,
                                                     int K, int N) {
  __shared__ float tile[64][65];
  const int n0 = blockIdx.x * 64, k0 = blockIdx.y * 64;
  const int tid = threadIdx.x;
#pragma unroll
  for (int i = 0; i < 16; ++i) {
    int idx = tid + i * 256;
    int r = idx >> 6, c = idx & 63;
    tile[r][c] = W[(size_t)(k0 + r) * N + n0 + c];
  }
  __syncthreads();
#pragma unroll
  for (int i = 0; i < 16; ++i) {
    int idx = tid + i * 256;
    int r = idx >> 6, c = idx & 63;
    Wt[(size_t)(n0 + r) * K + k0 + c] = __float2bfloat16(tile[c][r]);
  }
}

// ---------------- LN0: values f32 -> h bf16 (4 rows/block, wave per row) ----------------
__global__ __launch_bounds__(256) void ln0_kernel(const float* __restrict__ x,
                                                  const float* __restrict__ g,
                                                  const float* __restrict__ bt,
                                                  hbf* __restrict__ h) {
  const int row = blockIdx.x * 4 + (threadIdx.x >> 6);
  const int l = threadIdx.x & 63;
  const float* xr = x + (size_t)row * 512;
  float v[8], s = 0.f, s2 = 0.f;
#pragma unroll
  for (int i = 0; i < 8; ++i) {
    float t = xr[l + 64 * i];
    v[i] = t; s += t; s2 += t * t;
  }
#pragma unroll
  for (int off = 32; off; off >>= 1) { s += __shfl_xor(s, off); s2 += __shfl_xor(s2, off); }
  float mu = s * (1.f / 512.f);
  float rs = rsqrtf(s2 * (1.f / 512.f) - mu * mu + 1e-3f);
  hbf* hr = h + (size_t)row * 512;
#pragma unroll
  for (int i = 0; i < 8; ++i) {
    int c = l + 64 * i;
    hr[c] = __float2bfloat16((v[i] - mu) * rs * g[c] + bt[c]);
  }
}

// ---------------- residual add + LN1 (4 rows/block) ----------------
__global__ __launch_bounds__(256) void lnadd_kernel(const float* __restrict__ values,
                                                    const float* __restrict__ obuf,
                                                    const float* __restrict__ g,
                                                    const float* __restrict__ bt,
                                                    float* __restrict__ res1,
                                                    hbf* __restrict__ h2) {
  const int row = blockIdx.x * 4 + (threadIdx.x >> 6);
  const int l = threadIdx.x & 63;
  const float* vr = values + (size_t)row * 512;
  const float* orow = obuf + (size_t)row * 512;
  float* rr = res1 + (size_t)row * 512;
  float v[8], s = 0.f, s2 = 0.f;
#pragma unroll
  for (int i = 0; i < 8; ++i) {
    int c = l + 64 * i;
    float t = vr[c] + orow[c];
    v[i] = t; s += t; s2 += t * t;
    rr[c] = t;
  }
#pragma unroll
  for (int off = 32; off; off >>= 1) { s += __shfl_xor(s, off); s2 += __shfl_xor(s2, off); }
  float mu = s * (1.f / 512.f);
  float rs = rsqrtf(s2 * (1.f / 512.f) - mu * mu + 1e-3f);
  hbf* hr = h2 + (size_t)row * 512;
#pragma unroll
  for (int i = 0; i < 8; ++i) {
    int c = l + 64 * i;
    hr[c] = __float2bfloat16((v[i] - mu) * rs * g[c] + bt[c]);
  }
}

// ---------------- GEMM: A[M][K] bf16, Bt[N][K] bf16, BM=128 BN=64 BK=64 ----------------
// EPI 0: out bf16 = relu(acc+bias) ; EPI 1: out bf16 = acc+bias ; EPI 2: out f32 = acc+bias+resid
template <int EPI>
__global__ __launch_bounds__(256) void gemm_bt(const hbf* __restrict__ A,
                                               const hbf* __restrict__ Bt,
                                               const float* __restrict__ bias,
                                               const float* __restrict__ resid,
                                               void* __restrict__ outp,
                                               int M, int N, int K) {
  __shared__ hbf As[128 * 64];  // 16 KB, row stride 128B, XOR-swizzled slots
  __shared__ hbf Bs[64 * 64];   // 8 KB
  const int tid = threadIdx.x;
  const int lane = tid & 63;
  const int w = tid >> 6;
  const int wm = w >> 1, wn = w & 1;

  // XCD-aware bijective swizzle (all grids are multiples of 8 blocks)
  const int nbx = gridDim.x;
  const int nwg = nbx * gridDim.y;
  const int bid = blockIdx.y * nbx + blockIdx.x;
  const int cpx = nwg >> 3;
  const int sw = (bid & 7) * cpx + (bid >> 3);
  const int m0 = (sw / nbx) * 128, n0 = (sw % nbx) * 64;

  f32x4 acc[4][2] = {};

  // staging: linear LDS dest, inverse-swizzled global source chunk
  int ar[4], ac[4];
#pragma unroll
  for (int p = 0; p < 4; ++p) {
    int off = p * 4096 + tid * 16;
    int r = off >> 7, sl = (off >> 4) & 7;
    ar[p] = r;
    ac[p] = sl ^ (r & 7);
  }

  for (int kt = 0; kt < K; kt += 64) {
#pragma unroll
    for (int p = 0; p < 4; ++p)
      async_copy16(A + (size_t)(m0 + ar[p]) * K + kt + ac[p] * 8,
                   (char*)As + p * 4096 + tid * 16);
#pragma unroll
    for (int p = 0; p < 2; ++p)
      async_copy16(Bt + (size_t)(n0 + ar[p]) * K + kt + ac[p] * 8,
                   (char*)Bs + p * 4096 + tid * 16);
    __syncthreads();
    const int cq = lane >> 4, lr = lane & 15;
    bf16x8 af[2][4], bg[2][2];
#pragma unroll
    for (int i = 0; i < 4; ++i) {
      int m = wm * 64 + i * 16 + lr;
#pragma unroll
      for (int kk = 0; kk < 2; ++kk) {
        int sl = (kk * 4 + cq) ^ (m & 7);
        af[kk][i] = *reinterpret_cast<const bf16x8*>((const char*)As + m * 128 + sl * 16);
      }
    }
#pragma unroll
    for (int j = 0; j < 2; ++j) {
      int n = wn * 32 + j * 16 + lr;
#pragma unroll
      for (int kk = 0; kk < 2; ++kk) {
        int sl = (kk * 4 + cq) ^ (n & 7);
        bg[kk][j] = *reinterpret_cast<const bf16x8*>((const char*)Bs + n * 128 + sl * 16);
      }
    }
#pragma unroll
    for (int kk = 0; kk < 2; ++kk)
#pragma unroll
      for (int i = 0; i < 4; ++i)
#pragma unroll
        for (int j = 0; j < 2; ++j)
          acc[i][j] = MFMA16(af[kk][i], bg[kk][j], acc[i][j]);
    __syncthreads();
  }

#pragma unroll
  for (int j = 0; j < 2; ++j) {
    int col = n0 + wn * 32 + j * 16 + (lane & 15);
    float bcol = bias[col];
#pragma unroll
    for (int i = 0; i < 4; ++i) {
      int rowb = m0 + wm * 64 + i * 16 + (lane >> 4) * 4;
#pragma unroll
      for (int r = 0; r < 4; ++r) {
        int row = rowb + r;
        float v = acc[i][j][r] + bcol;
        if (EPI == 0) {
          v = v > 0.f ? v : 0.f;
          ((hbf*)outp)[(size_t)row * N + col] = __float2bfloat16(v);
        } else if (EPI == 1) {
          ((hbf*)outp)[(size_t)row * N + col] = __float2bfloat16(v);
        } else {
          ((float*)outp)[(size_t)row * N + col] = v + resid[(size_t)row * N + col];
        }
      }
    }
  }
}

// ---------------- V transpose: X2 v-slice -> vT[bh][64 d][512 s] bf16 ----------------
__global__ __launch_bounds__(256) void vtrans_kernel(const hbf* __restrict__ X2,
                                                     hbf* __restrict__ vT) {
  __shared__ hbf tile[64][80];
  const int bh = blockIdx.x, s0 = blockIdx.y * 64;
  const int b = bh >> 3, h = bh & 7;
  const int tid = threadIdx.x;
#pragma unroll
  for (int i = 0; i < 2; ++i) {
    int chunk = tid + i * 256;
    int r = chunk >> 3, c8 = (chunk & 7) * 8;
    const hbf* src = X2 + (size_t)(b * 512 + s0 + r) * 1536 + h * 192 + 128 + c8;
    *reinterpret_cast<bf16x8*>(&tile[r][c8]) = *reinterpret_cast<const bf16x8*>(src);
  }
  __syncthreads();
#pragma unroll
  for (int i = 0; i < 2; ++i) {
    int chunk = tid + i * 256;
    int d = chunk >> 3, s8 = (chunk & 7) * 8;
    bf16x8 v;
#pragma unroll
    for (int j = 0; j < 8; ++j) v[j] = *reinterpret_cast<const __bf16*>(&tile[s8 + j][d]);
    *reinterpret_cast<bf16x8*>(vT + ((size_t)bh * 64 + d) * 512 + s0 + s8) = v;
  }
}

// ---------------- relative-position bias: bb[c][bh][q] = q . (Wp[c]+bp)|_h ----------------
__global__ __launch_bounds__(256) void posbias_kernel(const hbf* __restrict__ X2,
                                                      const float* __restrict__ Wp,
                                                      const float* __restrict__ bp,
                                                      float* __restrict__ bb) {
  int idx = blockIdx.x * 256 + threadIdx.x;  // 3*64*512 = 98304
  int c = idx >> 15;
  int r = idx & 32767;
  int bh = r >> 9, q = r & 511;
  int b = bh >> 3, h = bh & 7;
  const hbf* qp = X2 + (size_t)(b * 512 + q) * 1536 + h * 192;
  const float* wr = Wp + c * 512 + h * 64;
  const float* br = bp + h * 64;
  float s = 0.f;
#pragma unroll
  for (int d8 = 0; d8 < 8; ++d8) {
    bf16x8 qv = *reinterpret_cast<const bf16x8*>(qp + d8 * 8);
#pragma unroll
    for (int j = 0; j < 8; ++j) s += (float)qv[j] * (wr[d8 * 8 + j] + br[d8 * 8 + j]);
  }
  bb[idx] = s;
}

// ---------------- causal flash attention with degenerate relative bias ----------------
__global__ __launch_bounds__(256) void attn_kernel(const hbf* __restrict__ X2,
                                                   const hbf* __restrict__ vT,
                                                   const float* __restrict__ bb,
                                                   float* __restrict__ obuf) {
  __shared__ hbf p_lds[4][16][32];
  const int bh = blockIdx.x;
  const int b = bh >> 3, h = bh & 7;
  const int q0 = blockIdx.y * 64;
  const int tid = threadIdx.x;
  const int lane = tid & 63, w = tid >> 6;
  const int qbase = q0 + w * 16;

  bf16x8 qa[2];
  {
    int qrow = qbase + (lane & 15);
    const hbf* qp = X2 + (size_t)(b * 512 + qrow) * 1536 + h * 192 + (lane >> 4) * 8;
#pragma unroll
    for (int c = 0; c < 2; ++c) qa[c] = *reinterpret_cast<const bf16x8*>(qp + c * 32);
  }
  float bias0[4], bias1[4];
#pragma unroll
  for (int r = 0; r < 4; ++r) {
    int qr = qbase + (lane >> 4) * 4 + r;
    bias0[r] = bb[bh * 512 + qr];
    bias1[r] = bb[32768 + bh * 512 + qr];
  }

  float mrow[4], lsum[4];
  f32x4 oacc[4];
#pragma unroll
  for (int r = 0; r < 4; ++r) { mrow[r] = -1e30f; lsum[r] = 0.f; }
#pragma unroll
  for (int nt = 0; nt < 4; ++nt) oacc[nt] = (f32x4){0.f, 0.f, 0.f, 0.f};

  const int qhi = qbase + 15;
  const int nchunks = (qhi >> 5) + 1;
  for (int ch = 0; ch < nchunks; ++ch) {
    const int k32 = ch * 32;
    f32x4 z = {0.f, 0.f, 0.f, 0.f};
    f32x4 s0, s1;
    {
      const hbf* kp = X2 + (size_t)(b * 512 + k32 + (lane & 15)) * 1536 + h * 192 + 64 + (lane >> 4) * 8;
      bf16x8 kb = *reinterpret_cast<const bf16x8*>(kp);
      s0 = MFMA16(qa[0], kb, z);
      kb = *reinterpret_cast<const bf16x8*>(kp + 32);
      s0 = MFMA16(qa[1], kb, s0);
      const hbf* kp1 = kp + 16 * 1536;
      kb = *reinterpret_cast<const bf16x8*>(kp1);
      s1 = MFMA16(qa[0], kb, z);
      kb = *reinterpret_cast<const bf16x8*>(kp1 + 32);
      s1 = MFMA16(qa[1], kb, s1);
    }
    const int col0 = k32 + (lane & 15);
    const int col1 = col0 + 16;
    float p0[4], p1[4], alpha[4];
#pragma unroll
    for (int r = 0; r < 4; ++r) {
      int q = qbase + (lane >> 4) * 4 + r;
      float sc0 = (col0 > q) ? -1e30f : (s0[r] * 0.125f + (col0 == q ? bias1[r] : bias0[r]));
      float sc1 = (col1 > q) ? -1e30f : (s1[r] * 0.125f + (col1 == q ? bias1[r] : bias0[r]));
      float cm = fmaxf(sc0, sc1);
#pragma unroll
      for (int off = 1; off < 16; off <<= 1) cm = fmaxf(cm, __shfl_xor(cm, off));
      float mn = fmaxf(mrow[r], cm);
      alpha[r] = __expf(mrow[r] - mn);
      mrow[r] = mn;
      float e0 = __expf(sc0 - mn), e1 = __expf(sc1 - mn);
      p0[r] = e0; p1[r] = e1;
      float ps = e0 + e1;
#pragma unroll
      for (int off = 1; off < 16; off <<= 1) ps += __shfl_xor(ps, off);
      lsum[r] = lsum[r] * alpha[r] + ps;
    }
#pragma unroll
    for (int nt = 0; nt < 4; ++nt)
#pragma unroll
      for (int r = 0; r < 4; ++r) oacc[nt][r] *= alpha[r];
#pragma unroll
    for (int r = 0; r < 4; ++r) {
      p_lds[w][(lane >> 4) * 4 + r][lane & 15] = __float2bfloat16(p0[r]);
      p_lds[w][(lane >> 4) * 4 + r][16 + (lane & 15)] = __float2bfloat16(p1[r]);
    }
    bf16x8 pa = *reinterpret_cast<const bf16x8*>(&p_lds[w][lane & 15][(lane >> 4) * 8]);
#pragma unroll
    for (int nt = 0; nt < 4; ++nt) {
      const hbf* vp = vT + ((size_t)bh * 64 + nt * 16 + (lane & 15)) * 512 + k32 + (lane >> 4) * 8;
      bf16x8 vb = *reinterpret_cast<const bf16x8*>(vp);
      oacc[nt] = MFMA16(pa, vb, oacc[nt]);
    }
  }
#pragma unroll
  for (int r = 0; r < 4; ++r) {
    float rl = 1.f / lsum[r];
    int q = qbase + (lane >> 4) * 4 + r;
    float* orow = obuf + (size_t)(b * 512 + q) * 512 + h * 64;
#pragma unroll
    for (int nt = 0; nt < 4; ++nt) orow[nt * 16 + (lane & 15)] = oacc[nt][r] * rl;
  }
}

extern "C" void kernel_launch(void* const* d_in, const int* in_sizes, int n_in,
                              void* d_out, int out_size, void* d_ws, size_t ws_size,
                              hipStream_t stream) {
  const float* values = (const float*)d_in[0];
  const float* ln0_g = (const float*)d_in[2];
  const float* ln0_b = (const float*)d_in[3];
  const float* W0a = (const float*)d_in[4];
  const float* b0a = (const float*)d_in[5];
  const float* W0b = (const float*)d_in[6];
  const float* b0b = (const float*)d_in[7];
  const float* Wp = (const float*)d_in[8];
  const float* bp = (const float*)d_in[9];
  const float* ln1_g = (const float*)d_in[10];
  const float* ln1_b = (const float*)d_in[11];
  const float* W1a = (const float*)d_in[12];
  const float* b1a = (const float*)d_in[13];
  const float* W1b = (const float*)d_in[14];
  const float* b1b = (const float*)d_in[15];

  char* ws = (char*)d_ws;
  hbf* W0a_t = (hbf*)(ws + (0ull << 20));
  hbf* W0b_t = (hbf*)(ws + (2ull << 20));
  hbf* W1a_t = (hbf*)(ws + (8ull << 20));
  hbf* W1b_t = (hbf*)(ws + (10ull << 20));
  hbf* hbuf = (hbf*)(ws + (12ull << 20));   // LN0 out, reused as h2
  hbf* X1 = (hbf*)(ws + (16ull << 20));     // 16MB, reused as X3
  hbf* X2 = (hbf*)(ws + (32ull << 20));     // 12MB (QKV)
  float* obuf = (float*)(ws + (44ull << 20));  // 8MB
  hbf* vT = (hbf*)(ws + (52ull << 20));     // 4MB
  float* bb = (float*)(ws + (56ull << 20)); // 384KB
  float* res1 = (float*)(ws + (57ull << 20));  // 8MB
  hbf* X3 = X1;
  hbf* h2 = hbuf;

  wtrans_kernel<<<dim3(32, 8), 256, 0, stream>>>(W0a, W0a_t, 512, 2048);
  wtrans_kernel<<<dim3(24, 32), 256, 0, stream>>>(W0b, W0b_t, 2048, 1536);
  wtrans_kernel<<<dim3(32, 8), 256, 0, stream>>>(W1a, W1a_t, 512, 2048);
  wtrans_kernel<<<dim3(8, 32), 256, 0, stream>>>(W1b, W1b_t, 2048, 512);

  ln0_kernel<<<1024, 256, 0, stream>>>(values, ln0_g, ln0_b, hbuf);

  gemm_bt<0><<<dim3(32, 32), 256, 0, stream>>>(hbuf, W0a_t, b0a, nullptr, X1, 4096, 2048, 512);
  gemm_bt<1><<<dim3(24, 32), 256, 0, stream>>>(X1, W0b_t, b0b, nullptr, X2, 4096, 1536, 2048);

  vtrans_kernel<<<dim3(64, 8), 256, 0, stream>>>(X2, vT);
  posbias_kernel<<<384, 256, 0, stream>>>(X2, Wp, bp, bb);
  attn_kernel<<<dim3(64, 8), 256, 0, stream>>>(X2, vT, bb, obuf);

  lnadd_kernel<<<1024, 256, 0, stream>>>(values, obuf, ln1_g, ln1_b, res1, h2);

  gemm_bt<0><<<dim3(32, 32), 256, 0, stream>>>(h2, W1a_t, b1a, nullptr, X3, 4096, 2048, 512);
  gemm_bt<2><<<dim3(8, 32), 256, 0, stream>>>(X3, W1b_t, b1b, res1, (float*)d_out, 4096, 512, 2048);
}

// Round 7
// 232.258 us; speedup vs baseline: 1.2258x; 1.0644x over previous
//
#include <hip/hip_runtime.h>
#include <hip/hip_bf16.h>
#include <stdint.h>

using hbf = __hip_bfloat16;
typedef __bf16 bf16x8 __attribute__((ext_vector_type(8)));
typedef float f32x4 __attribute__((ext_vector_type(4)));

#define MFMA16(a, b, c) __builtin_amdgcn_mfma_f32_16x16x32_bf16((a), (b), (c), 0, 0, 0)

__device__ __forceinline__ void async_copy16(const void* gsrc, void* ldst) {
  __builtin_amdgcn_global_load_lds((const __attribute__((address_space(1))) void*)gsrc,
                                   (__attribute__((address_space(3))) void*)ldst,
                                   16, 0, 0);
}

// ---------------- fused weight cast+transpose: 4 weights, one launch ----------------
__global__ __launch_bounds__(256) void wtrans_all(const float* __restrict__ W0a,
                                                  const float* __restrict__ W0b,
                                                  const float* __restrict__ W1a,
                                                  const float* __restrict__ W1b,
                                                  hbf* __restrict__ T0a, hbf* __restrict__ T0b,
                                                  hbf* __restrict__ T1a, hbf* __restrict__ T1b) {
  __shared__ float tile[64][65];
  const int idx = blockIdx.x;
  const float* W; hbf* Wt; int K, N, nt, i;
  if (idx < 256)        { W = W0a; Wt = T0a; K = 512;  N = 2048; nt = 32; i = idx; }
  else if (idx < 1024)  { W = W0b; Wt = T0b; K = 2048; N = 1536; nt = 24; i = idx - 256; }
  else if (idx < 1280)  { W = W1a; Wt = T1a; K = 512;  N = 2048; nt = 32; i = idx - 1024; }
  else                  { W = W1b; Wt = T1b; K = 2048; N = 512;  nt = 8;  i = idx - 1280; }
  const int n0 = (i % nt) * 64, k0 = (i / nt) * 64;
  const int tid = threadIdx.x;
#pragma unroll
  for (int t = 0; t < 16; ++t) {
    int q = tid + t * 256;
    int r = q >> 6, c = q & 63;
    tile[r][c] = W[(size_t)(k0 + r) * N + n0 + c];
  }
  __syncthreads();
#pragma unroll
  for (int t = 0; t < 16; ++t) {
    int q = tid + t * 256;
    int r = q >> 6, c = q & 63;
    Wt[(size_t)(n0 + r) * K + k0 + c] = __float2bfloat16(tile[c][r]);
  }
}

// ---------------- LN0: values f32 -> h bf16 (4 rows/block, wave per row) ----------------
__global__ __launch_bounds__(256) void ln0_kernel(const float* __restrict__ x,
                                                  const float* __restrict__ g,
                                                  const float* __restrict__ bt,
                                                  hbf* __restrict__ h) {
  const int row = blockIdx.x * 4 + (threadIdx.x >> 6);
  const int l = threadIdx.x & 63;
  const float* xr = x + (size_t)row * 512;
  float v[8], s = 0.f, s2 = 0.f;
#pragma unroll
  for (int i = 0; i < 8; ++i) {
    float t = xr[l + 64 * i];
    v[i] = t; s += t; s2 += t * t;
  }
#pragma unroll
  for (int off = 32; off; off >>= 1) { s += __shfl_xor(s, off); s2 += __shfl_xor(s2, off); }
  float mu = s * (1.f / 512.f);
  float rs = rsqrtf(s2 * (1.f / 512.f) - mu * mu + 1e-3f);
  hbf* hr = h + (size_t)row * 512;
#pragma unroll
  for (int i = 0; i < 8; ++i) {
    int c = l + 64 * i;
    hr[c] = __float2bfloat16((v[i] - mu) * rs * g[c] + bt[c]);
  }
}

// ---------------- residual add + LN1 (4 rows/block) ----------------
__global__ __launch_bounds__(256) void lnadd_kernel(const float* __restrict__ values,
                                                    const float* __restrict__ obuf,
                                                    const float* __restrict__ g,
                                                    const float* __restrict__ bt,
                                                    float* __restrict__ res1,
                                                    hbf* __restrict__ h2) {
  const int row = blockIdx.x * 4 + (threadIdx.x >> 6);
  const int l = threadIdx.x & 63;
  const float* vr = values + (size_t)row * 512;
  const float* orow = obuf + (size_t)row * 512;
  float* rr = res1 + (size_t)row * 512;
  float v[8], s = 0.f, s2 = 0.f;
#pragma unroll
  for (int i = 0; i < 8; ++i) {
    int c = l + 64 * i;
    float t = vr[c] + orow[c];
    v[i] = t; s += t; s2 += t * t;
    rr[c] = t;
  }
#pragma unroll
  for (int off = 32; off; off >>= 1) { s += __shfl_xor(s, off); s2 += __shfl_xor(s2, off); }
  float mu = s * (1.f / 512.f);
  float rs = rsqrtf(s2 * (1.f / 512.f) - mu * mu + 1e-3f);
  hbf* hr = h2 + (size_t)row * 512;
#pragma unroll
  for (int i = 0; i < 8; ++i) {
    int c = l + 64 * i;
    hr[c] = __float2bfloat16((v[i] - mu) * rs * g[c] + bt[c]);
  }
}

// ---------------- GEMM: A[M][K] bf16, Bt[N][K] bf16, BM=128, BK=64, 2-phase dbuf ----------------
// EPI 0: bf16 relu(acc+bias); EPI 1: bf16 acc+bias; EPI 2: f32 acc+bias+resid
template <int EPI, int BN>
__global__ __launch_bounds__(256) void gemm_bt(const hbf* __restrict__ A,
                                               const hbf* __restrict__ Bt,
                                               const float* __restrict__ bias,
                                               const float* __restrict__ resid,
                                               void* __restrict__ outp,
                                               int M, int N, int K) {
  constexpr int WCOLS = (BN == 64) ? 2 : 1;
  constexpr int WROWS = 4 / WCOLS;
  constexpr int MI = 128 / (WROWS * 16);
  constexpr int NJ = BN / (WCOLS * 16);
  constexpr int BCH = BN / 32;  // B staging chunks per thread
  __shared__ hbf As[2][128 * 64];
  __shared__ hbf Bs[2][BN * 64];
  const int tid = threadIdx.x;
  const int lane = tid & 63;
  const int w = tid >> 6;
  const int wm = w / WCOLS, wn = w % WCOLS;

  // XCD-aware bijective swizzle (all grids are multiples of 8 blocks)
  const int nbx = gridDim.x;
  const int nwg = nbx * gridDim.y;
  const int bid = blockIdx.y * nbx + blockIdx.x;
  const int cpx = nwg >> 3;
  const int sw = (bid & 7) * cpx + (bid >> 3);
  const int m0 = (sw / nbx) * 128, n0 = (sw % nbx) * BN;

  f32x4 acc[MI][NJ] = {};

  // staging: linear LDS dest, inverse-swizzled global source chunk
  int ar[4], ac[4];
#pragma unroll
  for (int p = 0; p < 4; ++p) {
    int off = p * 4096 + tid * 16;
    int r = off >> 7, sl = (off >> 4) & 7;
    ar[p] = r;
    ac[p] = sl ^ (r & 7);
  }

  auto stage = [&](int buf, int kt) {
#pragma unroll
    for (int p = 0; p < 4; ++p)
      async_copy16(A + (size_t)(m0 + ar[p]) * K + kt + ac[p] * 8,
                   (char*)As[buf] + p * 4096 + tid * 16);
#pragma unroll
    for (int p = 0; p < BCH; ++p)
      async_copy16(Bt + (size_t)(n0 + ar[p]) * K + kt + ac[p] * 8,
                   (char*)Bs[buf] + p * 4096 + tid * 16);
  };

  stage(0, 0);
  __syncthreads();  // compiler drains vmcnt(0) before s_barrier
  int cur = 0;

  for (int kt = 0; kt < K; kt += 64) {
    if (kt + 64 < K) stage(cur ^ 1, kt + 64);  // prefetch next tile; latency hides under MFMA
    const int cq = lane >> 4, lr = lane & 15;
    bf16x8 af[2][MI], bg[2][NJ];
#pragma unroll
    for (int i = 0; i < MI; ++i) {
      int m = wm * (MI * 16) + i * 16 + lr;
#pragma unroll
      for (int kk = 0; kk < 2; ++kk) {
        int sl = (kk * 4 + cq) ^ (m & 7);
        af[kk][i] = *reinterpret_cast<const bf16x8*>((const char*)As[cur] + m * 128 + sl * 16);
      }
    }
#pragma unroll
    for (int j = 0; j < NJ; ++j) {
      int n = wn * (NJ * 16) + j * 16 + lr;
#pragma unroll
      for (int kk = 0; kk < 2; ++kk) {
        int sl = (kk * 4 + cq) ^ (n & 7);
        bg[kk][j] = *reinterpret_cast<const bf16x8*>((const char*)Bs[cur] + n * 128 + sl * 16);
      }
    }
#pragma unroll
    for (int kk = 0; kk < 2; ++kk)
#pragma unroll
      for (int i = 0; i < MI; ++i)
#pragma unroll
        for (int j = 0; j < NJ; ++j)
          acc[i][j] = MFMA16(af[kk][i], bg[kk][j], acc[i][j]);
    __syncthreads();  // drains prefetch vmcnt + publishes buffers
    cur ^= 1;
  }

#pragma unroll
  for (int j = 0; j < NJ; ++j) {
    int col = n0 + wn * (NJ * 16) + j * 16 + (lane & 15);
    float bcol = bias[col];
#pragma unroll
    for (int i = 0; i < MI; ++i) {
      int rowb = m0 + wm * (MI * 16) + i * 16 + (lane >> 4) * 4;
#pragma unroll
      for (int r = 0; r < 4; ++r) {
        int row = rowb + r;
        float v = acc[i][j][r] + bcol;
        if (EPI == 0) {
          v = v > 0.f ? v : 0.f;
          ((hbf*)outp)[(size_t)row * N + col] = __float2bfloat16(v);
        } else if (EPI == 1) {
          ((hbf*)outp)[(size_t)row * N + col] = __float2bfloat16(v);
        } else {
          ((float*)outp)[(size_t)row * N + col] = v + resid[(size_t)row * N + col];
        }
      }
    }
  }
}

// ---------------- V transpose: X2 v-slice -> vT[bh][64 d][512 s] bf16 ----------------
__global__ __launch_bounds__(256) void vtrans_kernel(const hbf* __restrict__ X2,
                                                     hbf* __restrict__ vT) {
  __shared__ hbf tile[64][80];
  const int bh = blockIdx.x, s0 = blockIdx.y * 64;
  const int b = bh >> 3, h = bh & 7;
  const int tid = threadIdx.x;
#pragma unroll
  for (int i = 0; i < 2; ++i) {
    int chunk = tid + i * 256;
    int r = chunk >> 3, c8 = (chunk & 7) * 8;
    const hbf* src = X2 + (size_t)(b * 512 + s0 + r) * 1536 + h * 192 + 128 + c8;
    *reinterpret_cast<bf16x8*>(&tile[r][c8]) = *reinterpret_cast<const bf16x8*>(src);
  }
  __syncthreads();
#pragma unroll
  for (int i = 0; i < 2; ++i) {
    int chunk = tid + i * 256;
    int d = chunk >> 3, s8 = (chunk & 7) * 8;
    bf16x8 v;
#pragma unroll
    for (int j = 0; j < 8; ++j) v[j] = *reinterpret_cast<const __bf16*>(&tile[s8 + j][d]);
    *reinterpret_cast<bf16x8*>(vT + ((size_t)bh * 64 + d) * 512 + s0 + s8) = v;
  }
}

// ---------------- relative-position bias: bb[c][bh][q], c in {0,1} (c=2 causally dead) ----------------
__global__ __launch_bounds__(256) void posbias_kernel(const hbf* __restrict__ X2,
                                                      const float* __restrict__ Wp,
                                                      const float* __restrict__ bp,
                                                      float* __restrict__ bb) {
  int idx = blockIdx.x * 256 + threadIdx.x;  // 2*64*512 = 65536
  int c = idx >> 15;
  int r = idx & 32767;
  int bh = r >> 9, q = r & 511;
  int b = bh >> 3, h = bh & 7;
  const hbf* qp = X2 + (size_t)(b * 512 + q) * 1536 + h * 192;
  const float* wr = Wp + c * 512 + h * 64;
  const float* br = bp + h * 64;
  float s = 0.f;
#pragma unroll
  for (int d8 = 0; d8 < 8; ++d8) {
    bf16x8 qv = *reinterpret_cast<const bf16x8*>(qp + d8 * 8);
#pragma unroll
    for (int j = 0; j < 8; ++j) s += (float)qv[j] * (wr[d8 * 8 + j] + br[d8 * 8 + j]);
  }
  bb[idx] = s;
}

// ---------------- causal flash attention with degenerate relative bias ----------------
__global__ __launch_bounds__(256) void attn_kernel(const hbf* __restrict__ X2,
                                                   const hbf* __restrict__ vT,
                                                   const float* __restrict__ bb,
                                                   float* __restrict__ obuf) {
  __shared__ hbf p_lds[4][16][32];
  const int bh = blockIdx.x;
  const int b = bh >> 3, h = bh & 7;
  const int q0 = blockIdx.y * 64;
  const int tid = threadIdx.x;
  const int lane = tid & 63, w = tid >> 6;
  const int qbase = q0 + w * 16;

  bf16x8 qa[2];
  {
    int qrow = qbase + (lane & 15);
    const hbf* qp = X2 + (size_t)(b * 512 + qrow) * 1536 + h * 192 + (lane >> 4) * 8;
#pragma unroll
    for (int c = 0; c < 2; ++c) qa[c] = *reinterpret_cast<const bf16x8*>(qp + c * 32);
  }
  float bias0[4], bias1[4];
#pragma unroll
  for (int r = 0; r < 4; ++r) {
    int qr = qbase + (lane >> 4) * 4 + r;
    bias0[r] = bb[bh * 512 + qr];
    bias1[r] = bb[32768 + bh * 512 + qr];
  }

  float mrow[4], lsum[4];
  f32x4 oacc[4];
#pragma unroll
  for (int r = 0; r < 4; ++r) { mrow[r] = -1e30f; lsum[r] = 0.f; }
#pragma unroll
  for (int nt = 0; nt < 4; ++nt) oacc[nt] = (f32x4){0.f, 0.f, 0.f, 0.f};

  const int qhi = qbase + 15;
  const int nchunks = (qhi >> 5) + 1;
  for (int ch = 0; ch < nchunks; ++ch) {
    const int k32 = ch * 32;
    f32x4 z = {0.f, 0.f, 0.f, 0.f};
    f32x4 s0, s1;
    {
      const hbf* kp = X2 + (size_t)(b * 512 + k32 + (lane & 15)) * 1536 + h * 192 + 64 + (lane >> 4) * 8;
      bf16x8 kb = *reinterpret_cast<const bf16x8*>(kp);
      s0 = MFMA16(qa[0], kb, z);
      kb = *reinterpret_cast<const bf16x8*>(kp + 32);
      s0 = MFMA16(qa[1], kb, s0);
      const hbf* kp1 = kp + 16 * 1536;
      kb = *reinterpret_cast<const bf16x8*>(kp1);
      s1 = MFMA16(qa[0], kb, z);
      kb = *reinterpret_cast<const bf16x8*>(kp1 + 32);
      s1 = MFMA16(qa[1], kb, s1);
    }
    const int col0 = k32 + (lane & 15);
    const int col1 = col0 + 16;
    float p0[4], p1[4], alpha[4];
#pragma unroll
    for (int r = 0; r < 4; ++r) {
      int q = qbase + (lane >> 4) * 4 + r;
      float sc0 = (col0 > q) ? -1e30f : (s0[r] * 0.125f + (col0 == q ? bias1[r] : bias0[r]));
      float sc1 = (col1 > q) ? -1e30f : (s1[r] * 0.125f + (col1 == q ? bias1[r] : bias0[r]));
      float cm = fmaxf(sc0, sc1);
#pragma unroll
      for (int off = 1; off < 16; off <<= 1) cm = fmaxf(cm, __shfl_xor(cm, off));
      float mn = fmaxf(mrow[r], cm);
      alpha[r] = __expf(mrow[r] - mn);
      mrow[r] = mn;
      float e0 = __expf(sc0 - mn), e1 = __expf(sc1 - mn);
      p0[r] = e0; p1[r] = e1;
      float ps = e0 + e1;
#pragma unroll
      for (int off = 1; off < 16; off <<= 1) ps += __shfl_xor(ps, off);
      lsum[r] = lsum[r] * alpha[r] + ps;
    }
#pragma unroll
    for (int nt = 0; nt < 4; ++nt)
#pragma unroll
      for (int r = 0; r < 4; ++r) oacc[nt][r] *= alpha[r];
#pragma unroll
    for (int r = 0; r < 4; ++r) {
      p_lds[w][(lane >> 4) * 4 + r][lane & 15] = __float2bfloat16(p0[r]);
      p_lds[w][(lane >> 4) * 4 + r][16 + (lane & 15)] = __float2bfloat16(p1[r]);
    }
    bf16x8 pa = *reinterpret_cast<const bf16x8*>(&p_lds[w][lane & 15][(lane >> 4) * 8]);
#pragma unroll
    for (int nt = 0; nt < 4; ++nt) {
      const hbf* vp = vT + ((size_t)bh * 64 + nt * 16 + (lane & 15)) * 512 + k32 + (lane >> 4) * 8;
      bf16x8 vb = *reinterpret_cast<const bf16x8*>(vp);
      oacc[nt] = MFMA16(pa, vb, oacc[nt]);
    }
  }
#pragma unroll
  for (int r = 0; r < 4; ++r) {
    float rl = 1.f / lsum[r];
    int q = qbase + (lane >> 4) * 4 + r;
    float* orow = obuf + (size_t)(b * 512 + q) * 512 + h * 64;
#pragma unroll
    for (int nt = 0; nt < 4; ++nt) orow[nt * 16 + (lane & 15)] = oacc[nt][r] * rl;
  }
}

extern "C" void kernel_launch(void* const* d_in, const int* in_sizes, int n_in,
                              void* d_out, int out_size, void* d_ws, size_t ws_size,
                              hipStream_t stream) {
  const float* values = (const float*)d_in[0];
  const float* ln0_g = (const float*)d_in[2];
  const float* ln0_b = (const float*)d_in[3];
  const float* W0a = (const float*)d_in[4];
  const float* b0a = (const float*)d_in[5];
  const float* W0b = (const float*)d_in[6];
  const float* b0b = (const float*)d_in[7];
  const float* Wp = (const float*)d_in[8];
  const float* bp = (const float*)d_in[9];
  const float* ln1_g = (const float*)d_in[10];
  const float* ln1_b = (const float*)d_in[11];
  const float* W1a = (const float*)d_in[12];
  const float* b1a = (const float*)d_in[13];
  const float* W1b = (const float*)d_in[14];
  const float* b1b = (const float*)d_in[15];

  char* ws = (char*)d_ws;
  hbf* W0a_t = (hbf*)(ws + (0ull << 20));
  hbf* W0b_t = (hbf*)(ws + (2ull << 20));
  hbf* W1a_t = (hbf*)(ws + (8ull << 20));
  hbf* W1b_t = (hbf*)(ws + (10ull << 20));
  hbf* hbuf = (hbf*)(ws + (12ull << 20));   // LN0 out, reused as h2
  hbf* X1 = (hbf*)(ws + (16ull << 20));     // 16MB, reused as X3
  hbf* X2 = (hbf*)(ws + (32ull << 20));     // 12MB (QKV)
  float* obuf = (float*)(ws + (44ull << 20));  // 8MB
  hbf* vT = (hbf*)(ws + (52ull << 20));     // 4MB
  float* bb = (float*)(ws + (56ull << 20)); // 256KB
  float* res1 = (float*)(ws + (57ull << 20));  // 8MB
  hbf* X3 = X1;
  hbf* h2 = hbuf;

  wtrans_all<<<1536, 256, 0, stream>>>(W0a, W0b, W1a, W1b, W0a_t, W0b_t, W1a_t, W1b_t);

  ln0_kernel<<<1024, 256, 0, stream>>>(values, ln0_g, ln0_b, hbuf);

  gemm_bt<0, 64><<<dim3(32, 32), 256, 0, stream>>>(hbuf, W0a_t, b0a, nullptr, X1, 4096, 2048, 512);
  gemm_bt<1, 64><<<dim3(24, 32), 256, 0, stream>>>(X1, W0b_t, b0b, nullptr, X2, 4096, 1536, 2048);

  vtrans_kernel<<<dim3(64, 8), 256, 0, stream>>>(X2, vT);
  posbias_kernel<<<256, 256, 0, stream>>>(X2, Wp, bp, bb);
  attn_kernel<<<dim3(64, 8), 256, 0, stream>>>(X2, vT, bb, obuf);

  lnadd_kernel<<<1024, 256, 0, stream>>>(values, obuf, ln1_g, ln1_b, res1, h2);

  gemm_bt<0, 64><<<dim3(32, 32), 256, 0, stream>>>(h2, W1a_t, b1a, nullptr, X3, 4096, 2048, 512);
  gemm_bt<2, 32><<<dim3(16, 32), 256, 0, stream>>>(X3, W1b_t, b1b, res1, (float*)d_out, 4096, 512, 2048);
}

// Round 8
// 230.908 us; speedup vs baseline: 1.2329x; 1.0058x over previous
//
#include <hip/hip_runtime.h>
#include <hip/hip_bf16.h>
#include <stdint.h>

using hbf = __hip_bfloat16;
typedef __bf16 bf16x8 __attribute__((ext_vector_type(8)));
typedef float f32x4 __attribute__((ext_vector_type(4)));

#define MFMA16(a, b, c) __builtin_amdgcn_mfma_f32_16x16x32_bf16((a), (b), (c), 0, 0, 0)

__device__ __forceinline__ void async_copy16(const void* gsrc, void* ldst) {
  __builtin_amdgcn_global_load_lds((const __attribute__((address_space(1))) void*)gsrc,
                                   (__attribute__((address_space(3))) void*)ldst,
                                   16, 0, 0);
}

// ---------------- fused prep: 4 weight cast+transposes + LN0, one launch ----------------
__global__ __launch_bounds__(256) void prep_kernel(const float* __restrict__ W0a,
                                                   const float* __restrict__ W0b,
                                                   const float* __restrict__ W1a,
                                                   const float* __restrict__ W1b,
                                                   hbf* __restrict__ T0a, hbf* __restrict__ T0b,
                                                   hbf* __restrict__ T1a, hbf* __restrict__ T1b,
                                                   const float* __restrict__ x,
                                                   const float* __restrict__ g,
                                                   const float* __restrict__ bt,
                                                   hbf* __restrict__ h) {
  const int idx = blockIdx.x;
  const int tid = threadIdx.x;
  if (idx >= 1536) {  // ---- LN0: 4 rows/block ----
    const int row = (idx - 1536) * 4 + (tid >> 6);
    const int l = tid & 63;
    const float* xr = x + (size_t)row * 512;
    float v[8], s = 0.f, s2 = 0.f;
#pragma unroll
    for (int i = 0; i < 8; ++i) {
      float t = xr[l + 64 * i];
      v[i] = t; s += t; s2 += t * t;
    }
#pragma unroll
    for (int off = 32; off; off >>= 1) { s += __shfl_xor(s, off); s2 += __shfl_xor(s2, off); }
    float mu = s * (1.f / 512.f);
    float rs = rsqrtf(s2 * (1.f / 512.f) - mu * mu + 1e-3f);
    hbf* hr = h + (size_t)row * 512;
#pragma unroll
    for (int i = 0; i < 8; ++i) {
      int c = l + 64 * i;
      hr[c] = __float2bfloat16((v[i] - mu) * rs * g[c] + bt[c]);
    }
    return;
  }
  // ---- weight transpose ----
  __shared__ float tile[64][65];
  const float* W; hbf* Wt; int K, N, nt, i;
  if (idx < 256)        { W = W0a; Wt = T0a; K = 512;  N = 2048; nt = 32; i = idx; }
  else if (idx < 1024)  { W = W0b; Wt = T0b; K = 2048; N = 1536; nt = 24; i = idx - 256; }
  else if (idx < 1280)  { W = W1a; Wt = T1a; K = 512;  N = 2048; nt = 32; i = idx - 1024; }
  else                  { W = W1b; Wt = T1b; K = 2048; N = 512;  nt = 8;  i = idx - 1280; }
  const int n0 = (i % nt) * 64, k0 = (i / nt) * 64;
#pragma unroll
  for (int t = 0; t < 16; ++t) {
    int q = tid + t * 256;
    int r = q >> 6, c = q & 63;
    tile[r][c] = W[(size_t)(k0 + r) * N + n0 + c];
  }
  __syncthreads();
#pragma unroll
  for (int t = 0; t < 16; ++t) {
    int q = tid + t * 256;
    int r = q >> 6, c = q & 63;
    Wt[(size_t)(n0 + r) * K + k0 + c] = __float2bfloat16(tile[c][r]);
  }
}

// ---------------- residual add + LN1 (4 rows/block) ----------------
__global__ __launch_bounds__(256) void lnadd_kernel(const float* __restrict__ values,
                                                    const float* __restrict__ obuf,
                                                    const float* __restrict__ g,
                                                    const float* __restrict__ bt,
                                                    float* __restrict__ res1,
                                                    hbf* __restrict__ h2) {
  const int row = blockIdx.x * 4 + (threadIdx.x >> 6);
  const int l = threadIdx.x & 63;
  const float* vr = values + (size_t)row * 512;
  const float* orow = obuf + (size_t)row * 512;
  float* rr = res1 + (size_t)row * 512;
  float v[8], s = 0.f, s2 = 0.f;
#pragma unroll
  for (int i = 0; i < 8; ++i) {
    int c = l + 64 * i;
    float t = vr[c] + orow[c];
    v[i] = t; s += t; s2 += t * t;
    rr[c] = t;
  }
#pragma unroll
  for (int off = 32; off; off >>= 1) { s += __shfl_xor(s, off); s2 += __shfl_xor(s2, off); }
  float mu = s * (1.f / 512.f);
  float rs = rsqrtf(s2 * (1.f / 512.f) - mu * mu + 1e-3f);
  hbf* hr = h2 + (size_t)row * 512;
#pragma unroll
  for (int i = 0; i < 8; ++i) {
    int c = l + 64 * i;
    hr[c] = __float2bfloat16((v[i] - mu) * rs * g[c] + bt[c]);
  }
}

// ---------------- GEMM: BM=128 BK=64, 2-phase dbuf with COUNTED vmcnt (T4) ----------------
// EPI 0: bf16 relu(acc+bias); EPI 1: bf16 acc+bias; EPI 2: f32 acc+bias+resid
template <int EPI, int BN>
__global__ __launch_bounds__(256) void gemm_bt(const hbf* __restrict__ A,
                                               const hbf* __restrict__ Bt,
                                               const float* __restrict__ bias,
                                               const float* __restrict__ resid,
                                               void* __restrict__ outp,
                                               int M, int N, int K) {
  constexpr int WCOLS = (BN == 64) ? 2 : 1;
  constexpr int WROWS = 4 / WCOLS;
  constexpr int MI = 128 / (WROWS * 16);
  constexpr int NJ = BN / (WCOLS * 16);
  constexpr int BCH = BN / 32;  // B staging chunks per thread
  __shared__ hbf As[2][128 * 64];
  __shared__ hbf Bs[2][BN * 64];
  const int tid = threadIdx.x;
  const int lane = tid & 63;
  const int w = tid >> 6;
  const int wm = w / WCOLS, wn = w % WCOLS;

  // XCD-aware bijective swizzle (all grids are multiples of 8 blocks)
  const int nbx = gridDim.x;
  const int nwg = nbx * gridDim.y;
  const int bid = blockIdx.y * nbx + blockIdx.x;
  const int cpx = nwg >> 3;
  const int sw = (bid & 7) * cpx + (bid >> 3);
  const int m0 = (sw / nbx) * 128, n0 = (sw % nbx) * BN;

  f32x4 acc[MI][NJ] = {};

  // staging: linear LDS dest, inverse-swizzled global source chunk
  int ar[4], ac[4];
#pragma unroll
  for (int p = 0; p < 4; ++p) {
    int off = p * 4096 + tid * 16;
    int r = off >> 7, sl = (off >> 4) & 7;
    ar[p] = r;
    ac[p] = sl ^ (r & 7);
  }

  auto stage = [&](int buf, int kt) {
#pragma unroll
    for (int p = 0; p < 4; ++p)
      async_copy16(A + (size_t)(m0 + ar[p]) * K + kt + ac[p] * 8,
                   (char*)As[buf] + p * 4096 + tid * 16);
#pragma unroll
    for (int p = 0; p < BCH; ++p)
      async_copy16(Bt + (size_t)(n0 + ar[p]) * K + kt + ac[p] * 8,
                   (char*)Bs[buf] + p * 4096 + tid * 16);
  };

  stage(0, 0);
  int cur = 0;

  for (int kt = 0; kt < K; kt += 64) {
    // Issue next-tile prefetch, then wait ONLY for current tile's loads
    // (the 4+BCH newest outstanding ops are the prefetch; everything older
    //  -- i.e. cur's loads, issued a full iteration ago -- must have landed).
    if (kt + 64 < K) {
      stage(cur ^ 1, kt + 64);
      if constexpr (BN == 64) asm volatile("s_waitcnt vmcnt(6)" ::: "memory");
      else                    asm volatile("s_waitcnt vmcnt(5)" ::: "memory");
    } else {
      asm volatile("s_waitcnt vmcnt(0)" ::: "memory");  // no prefetch outstanding
    }
    __builtin_amdgcn_s_barrier();          // all waves: cur landed
    __builtin_amdgcn_sched_barrier(0);

    const int cq = lane >> 4, lr = lane & 15;
    bf16x8 af[2][MI], bg[2][NJ];
#pragma unroll
    for (int i = 0; i < MI; ++i) {
      int m = wm * (MI * 16) + i * 16 + lr;
#pragma unroll
      for (int kk = 0; kk < 2; ++kk) {
        int sl = (kk * 4 + cq) ^ (m & 7);
        af[kk][i] = *reinterpret_cast<const bf16x8*>((const char*)As[cur] + m * 128 + sl * 16);
      }
    }
#pragma unroll
    for (int j = 0; j < NJ; ++j) {
      int n = wn * (NJ * 16) + j * 16 + lr;
#pragma unroll
      for (int kk = 0; kk < 2; ++kk) {
        int sl = (kk * 4 + cq) ^ (n & 7);
        bg[kk][j] = *reinterpret_cast<const bf16x8*>((const char*)Bs[cur] + n * 128 + sl * 16);
      }
    }
#pragma unroll
    for (int kk = 0; kk < 2; ++kk)
#pragma unroll
      for (int i = 0; i < MI; ++i)
#pragma unroll
        for (int j = 0; j < NJ; ++j)
          acc[i][j] = MFMA16(af[kk][i], bg[kk][j], acc[i][j]);

    __builtin_amdgcn_sched_barrier(0);
    __builtin_amdgcn_s_barrier();          // all waves done reading cur (next iter overwrites it)
    cur ^= 1;
  }

#pragma unroll
  for (int j = 0; j < NJ; ++j) {
    int col = n0 + wn * (NJ * 16) + j * 16 + (lane & 15);
    float bcol = bias[col];
#pragma unroll
    for (int i = 0; i < MI; ++i) {
      int rowb = m0 + wm * (MI * 16) + i * 16 + (lane >> 4) * 4;
#pragma unroll
      for (int r = 0; r < 4; ++r) {
        int row = rowb + r;
        float v = acc[i][j][r] + bcol;
        if (EPI == 0) {
          v = v > 0.f ? v : 0.f;
          ((hbf*)outp)[(size_t)row * N + col] = __float2bfloat16(v);
        } else if (EPI == 1) {
          ((hbf*)outp)[(size_t)row * N + col] = __float2bfloat16(v);
        } else {
          ((float*)outp)[(size_t)row * N + col] = v + resid[(size_t)row * N + col];
        }
      }
    }
  }
}

// ---------------- fused post-QKV: V transpose (512 blocks) + pos-bias (256 blocks) ----------------
__global__ __launch_bounds__(256) void postqkv_kernel(const hbf* __restrict__ X2,
                                                      hbf* __restrict__ vT,
                                                      const float* __restrict__ Wp,
                                                      const float* __restrict__ bp,
                                                      float* __restrict__ bb) {
  const int blk = blockIdx.x;
  const int tid = threadIdx.x;
  if (blk < 512) {  // ---- V transpose ----
    __shared__ hbf tile[64][80];
    const int bh = blk >> 3, s0 = (blk & 7) * 64;
    const int b = bh >> 3, h = bh & 7;
#pragma unroll
    for (int i = 0; i < 2; ++i) {
      int chunk = tid + i * 256;
      int r = chunk >> 3, c8 = (chunk & 7) * 8;
      const hbf* src = X2 + (size_t)(b * 512 + s0 + r) * 1536 + h * 192 + 128 + c8;
      *reinterpret_cast<bf16x8*>(&tile[r][c8]) = *reinterpret_cast<const bf16x8*>(src);
    }
    __syncthreads();
#pragma unroll
    for (int i = 0; i < 2; ++i) {
      int chunk = tid + i * 256;
      int d = chunk >> 3, s8 = (chunk & 7) * 8;
      bf16x8 v;
#pragma unroll
      for (int j = 0; j < 8; ++j) v[j] = *reinterpret_cast<const __bf16*>(&tile[s8 + j][d]);
      *reinterpret_cast<bf16x8*>(vT + ((size_t)bh * 64 + d) * 512 + s0 + s8) = v;
    }
    return;
  }
  // ---- relative-position bias: bb[c][bh][q], c in {0,1} ----
  int idx = (blk - 512) * 256 + tid;  // 2*64*512 = 65536
  int c = idx >> 15;
  int r = idx & 32767;
  int bh = r >> 9, q = r & 511;
  int b = bh >> 3, h = bh & 7;
  const hbf* qp = X2 + (size_t)(b * 512 + q) * 1536 + h * 192;
  const float* wr = Wp + c * 512 + h * 64;
  const float* br = bp + h * 64;
  float s = 0.f;
#pragma unroll
  for (int d8 = 0; d8 < 8; ++d8) {
    bf16x8 qv = *reinterpret_cast<const bf16x8*>(qp + d8 * 8);
#pragma unroll
    for (int j = 0; j < 8; ++j) s += (float)qv[j] * (wr[d8 * 8 + j] + br[d8 * 8 + j]);
  }
  bb[idx] = s;
}

// ---------------- causal flash attention with degenerate relative bias ----------------
__global__ __launch_bounds__(256) void attn_kernel(const hbf* __restrict__ X2,
                                                   const hbf* __restrict__ vT,
                                                   const float* __restrict__ bb,
                                                   float* __restrict__ obuf) {
  __shared__ hbf p_lds[4][16][32];
  const int bh = blockIdx.x;
  const int b = bh >> 3, h = bh & 7;
  const int q0 = blockIdx.y * 64;
  const int tid = threadIdx.x;
  const int lane = tid & 63, w = tid >> 6;
  const int qbase = q0 + w * 16;

  bf16x8 qa[2];
  {
    int qrow = qbase + (lane & 15);
    const hbf* qp = X2 + (size_t)(b * 512 + qrow) * 1536 + h * 192 + (lane >> 4) * 8;
#pragma unroll
    for (int c = 0; c < 2; ++c) qa[c] = *reinterpret_cast<const bf16x8*>(qp + c * 32);
  }
  float bias0[4], bias1[4];
#pragma unroll
  for (int r = 0; r < 4; ++r) {
    int qr = qbase + (lane >> 4) * 4 + r;
    bias0[r] = bb[bh * 512 + qr];
    bias1[r] = bb[32768 + bh * 512 + qr];
  }

  float mrow[4], lsum[4];
  f32x4 oacc[4];
#pragma unroll
  for (int r = 0; r < 4; ++r) { mrow[r] = -1e30f; lsum[r] = 0.f; }
#pragma unroll
  for (int nt = 0; nt < 4; ++nt) oacc[nt] = (f32x4){0.f, 0.f, 0.f, 0.f};

  const int qhi = qbase + 15;
  const int nchunks = (qhi >> 5) + 1;
  for (int ch = 0; ch < nchunks; ++ch) {
    const int k32 = ch * 32;
    f32x4 z = {0.f, 0.f, 0.f, 0.f};
    f32x4 s0, s1;
    {
      const hbf* kp = X2 + (size_t)(b * 512 + k32 + (lane & 15)) * 1536 + h * 192 + 64 + (lane >> 4) * 8;
      bf16x8 kb = *reinterpret_cast<const bf16x8*>(kp);
      s0 = MFMA16(qa[0], kb, z);
      kb = *reinterpret_cast<const bf16x8*>(kp + 32);
      s0 = MFMA16(qa[1], kb, s0);
      const hbf* kp1 = kp + 16 * 1536;
      kb = *reinterpret_cast<const bf16x8*>(kp1);
      s1 = MFMA16(qa[0], kb, z);
      kb = *reinterpret_cast<const bf16x8*>(kp1 + 32);
      s1 = MFMA16(qa[1], kb, s1);
    }
    const int col0 = k32 + (lane & 15);
    const int col1 = col0 + 16;
    float p0[4], p1[4], alpha[4];
#pragma unroll
    for (int r = 0; r < 4; ++r) {
      int q = qbase + (lane >> 4) * 4 + r;
      float sc0 = (col0 > q) ? -1e30f : (s0[r] * 0.125f + (col0 == q ? bias1[r] : bias0[r]));
      float sc1 = (col1 > q) ? -1e30f : (s1[r] * 0.125f + (col1 == q ? bias1[r] : bias0[r]));
      float cm = fmaxf(sc0, sc1);
#pragma unroll
      for (int off = 1; off < 16; off <<= 1) cm = fmaxf(cm, __shfl_xor(cm, off));
      float mn = fmaxf(mrow[r], cm);
      alpha[r] = __expf(mrow[r] - mn);
      mrow[r] = mn;
      float e0 = __expf(sc0 - mn), e1 = __expf(sc1 - mn);
      p0[r] = e0; p1[r] = e1;
      float ps = e0 + e1;
#pragma unroll
      for (int off = 1; off < 16; off <<= 1) ps += __shfl_xor(ps, off);
      lsum[r] = lsum[r] * alpha[r] + ps;
    }
#pragma unroll
    for (int nt = 0; nt < 4; ++nt)
#pragma unroll
      for (int r = 0; r < 4; ++r) oacc[nt][r] *= alpha[r];
#pragma unroll
    for (int r = 0; r < 4; ++r) {
      p_lds[w][(lane >> 4) * 4 + r][lane & 15] = __float2bfloat16(p0[r]);
      p_lds[w][(lane >> 4) * 4 + r][16 + (lane & 15)] = __float2bfloat16(p1[r]);
    }
    bf16x8 pa = *reinterpret_cast<const bf16x8*>(&p_lds[w][lane & 15][(lane >> 4) * 8]);
#pragma unroll
    for (int nt = 0; nt < 4; ++nt) {
      const hbf* vp = vT + ((size_t)bh * 64 + nt * 16 + (lane & 15)) * 512 + k32 + (lane >> 4) * 8;
      bf16x8 vb = *reinterpret_cast<const bf16x8*>(vp);
      oacc[nt] = MFMA16(pa, vb, oacc[nt]);
    }
  }
#pragma unroll
  for (int r = 0; r < 4; ++r) {
    float rl = 1.f / lsum[r];
    int q = qbase + (lane >> 4) * 4 + r;
    float* orow = obuf + (size_t)(b * 512 + q) * 512 + h * 64;
#pragma unroll
    for (int nt = 0; nt < 4; ++nt) orow[nt * 16 + (lane & 15)] = oacc[nt][r] * rl;
  }
}

extern "C" void kernel_launch(void* const* d_in, const int* in_sizes, int n_in,
                              void* d_out, int out_size, void* d_ws, size_t ws_size,
                              hipStream_t stream) {
  const float* values = (const float*)d_in[0];
  const float* ln0_g = (const float*)d_in[2];
  const float* ln0_b = (const float*)d_in[3];
  const float* W0a = (const float*)d_in[4];
  const float* b0a = (const float*)d_in[5];
  const float* W0b = (const float*)d_in[6];
  const float* b0b = (const float*)d_in[7];
  const float* Wp = (const float*)d_in[8];
  const float* bp = (const float*)d_in[9];
  const float* ln1_g = (const float*)d_in[10];
  const float* ln1_b = (const float*)d_in[11];
  const float* W1a = (const float*)d_in[12];
  const float* b1a = (const float*)d_in[13];
  const float* W1b = (const float*)d_in[14];
  const float* b1b = (const float*)d_in[15];

  char* ws = (char*)d_ws;
  hbf* W0a_t = (hbf*)(ws + (0ull << 20));
  hbf* W0b_t = (hbf*)(ws + (2ull << 20));
  hbf* W1a_t = (hbf*)(ws + (8ull << 20));
  hbf* W1b_t = (hbf*)(ws + (10ull << 20));
  hbf* hbuf = (hbf*)(ws + (12ull << 20));   // LN0 out, reused as h2
  hbf* X1 = (hbf*)(ws + (16ull << 20));     // 16MB, reused as X3
  hbf* X2 = (hbf*)(ws + (32ull << 20));     // 12MB (QKV)
  float* obuf = (float*)(ws + (44ull << 20));  // 8MB
  hbf* vT = (hbf*)(ws + (52ull << 20));     // 4MB
  float* bb = (float*)(ws + (56ull << 20)); // 256KB
  float* res1 = (float*)(ws + (57ull << 20));  // 8MB
  hbf* X3 = X1;
  hbf* h2 = hbuf;

  prep_kernel<<<2560, 256, 0, stream>>>(W0a, W0b, W1a, W1b, W0a_t, W0b_t, W1a_t, W1b_t,
                                        values, ln0_g, ln0_b, hbuf);

  gemm_bt<0, 64><<<dim3(32, 32), 256, 0, stream>>>(hbuf, W0a_t, b0a, nullptr, X1, 4096, 2048, 512);
  gemm_bt<1, 64><<<dim3(24, 32), 256, 0, stream>>>(X1, W0b_t, b0b, nullptr, X2, 4096, 1536, 2048);

  postqkv_kernel<<<768, 256, 0, stream>>>(X2, vT, Wp, bp, bb);
  attn_kernel<<<dim3(64, 8), 256, 0, stream>>>(X2, vT, bb, obuf);

  lnadd_kernel<<<1024, 256, 0, stream>>>(values, obuf, ln1_g, ln1_b, res1, h2);

  gemm_bt<0, 64><<<dim3(32, 32), 256, 0, stream>>>(h2, W1a_t, b1a, nullptr, X3, 4096, 2048, 512);
  gemm_bt<2, 32><<<dim3(16, 32), 256, 0, stream>>>(X3, W1b_t, b1b, res1, (float*)d_out, 4096, 512, 2048);
}

// Round 9
// 226.407 us; speedup vs baseline: 1.2574x; 1.0199x over previous
//
#include <hip/hip_runtime.h>
#include <hip/hip_bf16.h>
#include <stdint.h>

using hbf = __hip_bfloat16;
typedef __bf16 bf16x8 __attribute__((ext_vector_type(8)));
typedef float f32x4 __attribute__((ext_vector_type(4)));

#define MFMA16(a, b, c) __builtin_amdgcn_mfma_f32_16x16x32_bf16((a), (b), (c), 0, 0, 0)

__device__ __forceinline__ void async_copy16(const void* gsrc, void* ldst) {
  __builtin_amdgcn_global_load_lds((const __attribute__((address_space(1))) void*)gsrc,
                                   (__attribute__((address_space(3))) void*)ldst,
                                   16, 0, 0);
}

// ---------------- fused prep: 4 weight cast+transposes + LN0, one launch ----------------
__global__ __launch_bounds__(256) void prep_kernel(const float* __restrict__ W0a,
                                                   const float* __restrict__ W0b,
                                                   const float* __restrict__ W1a,
                                                   const float* __restrict__ W1b,
                                                   hbf* __restrict__ T0a, hbf* __restrict__ T0b,
                                                   hbf* __restrict__ T1a, hbf* __restrict__ T1b,
                                                   const float* __restrict__ x,
                                                   const float* __restrict__ g,
                                                   const float* __restrict__ bt,
                                                   hbf* __restrict__ h) {
  const int idx = blockIdx.x;
  const int tid = threadIdx.x;
  if (idx >= 1536) {  // ---- LN0: 4 rows/block ----
    const int row = (idx - 1536) * 4 + (tid >> 6);
    const int l = tid & 63;
    const float* xr = x + (size_t)row * 512;
    float v[8], s = 0.f, s2 = 0.f;
#pragma unroll
    for (int i = 0; i < 8; ++i) {
      float t = xr[l + 64 * i];
      v[i] = t; s += t; s2 += t * t;
    }
#pragma unroll
    for (int off = 32; off; off >>= 1) { s += __shfl_xor(s, off); s2 += __shfl_xor(s2, off); }
    float mu = s * (1.f / 512.f);
    float rs = rsqrtf(s2 * (1.f / 512.f) - mu * mu + 1e-3f);
    hbf* hr = h + (size_t)row * 512;
#pragma unroll
    for (int i = 0; i < 8; ++i) {
      int c = l + 64 * i;
      hr[c] = __float2bfloat16((v[i] - mu) * rs * g[c] + bt[c]);
    }
    return;
  }
  // ---- weight transpose ----
  __shared__ float tile[64][65];
  const float* W; hbf* Wt; int K, N, nt, i;
  if (idx < 256)        { W = W0a; Wt = T0a; K = 512;  N = 2048; nt = 32; i = idx; }
  else if (idx < 1024)  { W = W0b; Wt = T0b; K = 2048; N = 1536; nt = 24; i = idx - 256; }
  else if (idx < 1280)  { W = W1a; Wt = T1a; K = 512;  N = 2048; nt = 32; i = idx - 1024; }
  else                  { W = W1b; Wt = T1b; K = 2048; N = 512;  nt = 8;  i = idx - 1280; }
  const int n0 = (i % nt) * 64, k0 = (i / nt) * 64;
#pragma unroll
  for (int t = 0; t < 16; ++t) {
    int q = tid + t * 256;
    int r = q >> 6, c = q & 63;
    tile[r][c] = W[(size_t)(k0 + r) * N + n0 + c];
  }
  __syncthreads();
#pragma unroll
  for (int t = 0; t < 16; ++t) {
    int q = tid + t * 256;
    int r = q >> 6, c = q & 63;
    Wt[(size_t)(n0 + r) * K + k0 + c] = __float2bfloat16(tile[c][r]);
  }
}

// ---------------- residual add + LN1 (4 rows/block) ----------------
__global__ __launch_bounds__(256) void lnadd_kernel(const float* __restrict__ values,
                                                    const float* __restrict__ obuf,
                                                    const float* __restrict__ g,
                                                    const float* __restrict__ bt,
                                                    float* __restrict__ res1,
                                                    hbf* __restrict__ h2) {
  const int row = blockIdx.x * 4 + (threadIdx.x >> 6);
  const int l = threadIdx.x & 63;
  const float* vr = values + (size_t)row * 512;
  const float* orow = obuf + (size_t)row * 512;
  float* rr = res1 + (size_t)row * 512;
  float v[8], s = 0.f, s2 = 0.f;
#pragma unroll
  for (int i = 0; i < 8; ++i) {
    int c = l + 64 * i;
    float t = vr[c] + orow[c];
    v[i] = t; s += t; s2 += t * t;
    rr[c] = t;
  }
#pragma unroll
  for (int off = 32; off; off >>= 1) { s += __shfl_xor(s, off); s2 += __shfl_xor(s2, off); }
  float mu = s * (1.f / 512.f);
  float rs = rsqrtf(s2 * (1.f / 512.f) - mu * mu + 1e-3f);
  hbf* hr = h2 + (size_t)row * 512;
#pragma unroll
  for (int i = 0; i < 8; ++i) {
    int c = l + 64 * i;
    hr[c] = __float2bfloat16((v[i] - mu) * rs * g[c] + bt[c]);
  }
}

// ---------------- GEMM: BM=128 BK=64, 2-phase dbuf, counted vmcnt ----------------
// EPI 0: bf16 relu(acc+bias); EPI 1: bf16 acc+bias; EPI 2: f32 acc+bias+resid
// EPI 3: QKV epilogue -- q/k col-blocks -> X2 bf16, v col-blocks -> vT transposed
template <int EPI, int BN>
__global__ __launch_bounds__(256) void gemm_bt(const hbf* __restrict__ A,
                                               const hbf* __restrict__ Bt,
                                               const float* __restrict__ bias,
                                               const float* __restrict__ resid,
                                               void* __restrict__ outp,
                                               hbf* __restrict__ outp2,
                                               int M, int N, int K) {
  constexpr int WCOLS = (BN == 64) ? 2 : 1;
  constexpr int WROWS = 4 / WCOLS;
  constexpr int MI = 128 / (WROWS * 16);
  constexpr int NJ = BN / (WCOLS * 16);
  constexpr int BCH = BN / 32;  // B staging chunks per thread
  __shared__ hbf As[2][128 * 64];
  __shared__ hbf Bs[2][BN * 64];
  const int tid = threadIdx.x;
  const int lane = tid & 63;
  const int w = tid >> 6;
  const int wm = w / WCOLS, wn = w % WCOLS;

  // XCD-aware bijective swizzle (all grids are multiples of 8 blocks)
  const int nbx = gridDim.x;
  const int nwg = nbx * gridDim.y;
  const int bid = blockIdx.y * nbx + blockIdx.x;
  const int cpx = nwg >> 3;
  const int sw = (bid & 7) * cpx + (bid >> 3);
  const int m0 = (sw / nbx) * 128, n0 = (sw % nbx) * BN;

  f32x4 acc[MI][NJ] = {};

  int ar[4], ac[4];
#pragma unroll
  for (int p = 0; p < 4; ++p) {
    int off = p * 4096 + tid * 16;
    int r = off >> 7, sl = (off >> 4) & 7;
    ar[p] = r;
    ac[p] = sl ^ (r & 7);
  }

  auto stage = [&](int buf, int kt) {
#pragma unroll
    for (int p = 0; p < 4; ++p)
      async_copy16(A + (size_t)(m0 + ar[p]) * K + kt + ac[p] * 8,
                   (char*)As[buf] + p * 4096 + tid * 16);
#pragma unroll
    for (int p = 0; p < BCH; ++p)
      async_copy16(Bt + (size_t)(n0 + ar[p]) * K + kt + ac[p] * 8,
                   (char*)Bs[buf] + p * 4096 + tid * 16);
  };

  stage(0, 0);
  int cur = 0;

  for (int kt = 0; kt < K; kt += 64) {
    if (kt + 64 < K) {
      stage(cur ^ 1, kt + 64);
      if constexpr (BN == 64) asm volatile("s_waitcnt vmcnt(6)" ::: "memory");
      else                    asm volatile("s_waitcnt vmcnt(5)" ::: "memory");
    } else {
      asm volatile("s_waitcnt vmcnt(0)" ::: "memory");
    }
    __builtin_amdgcn_s_barrier();
    __builtin_amdgcn_sched_barrier(0);

    const int cq = lane >> 4, lr = lane & 15;
    bf16x8 af[2][MI], bg[2][NJ];
#pragma unroll
    for (int i = 0; i < MI; ++i) {
      int m = wm * (MI * 16) + i * 16 + lr;
#pragma unroll
      for (int kk = 0; kk < 2; ++kk) {
        int sl = (kk * 4 + cq) ^ (m & 7);
        af[kk][i] = *reinterpret_cast<const bf16x8*>((const char*)As[cur] + m * 128 + sl * 16);
      }
    }
#pragma unroll
    for (int j = 0; j < NJ; ++j) {
      int n = wn * (NJ * 16) + j * 16 + lr;
#pragma unroll
      for (int kk = 0; kk < 2; ++kk) {
        int sl = (kk * 4 + cq) ^ (n & 7);
        bg[kk][j] = *reinterpret_cast<const bf16x8*>((const char*)Bs[cur] + n * 128 + sl * 16);
      }
    }
#pragma unroll
    for (int kk = 0; kk < 2; ++kk)
#pragma unroll
      for (int i = 0; i < MI; ++i)
#pragma unroll
        for (int j = 0; j < NJ; ++j)
          acc[i][j] = MFMA16(af[kk][i], bg[kk][j], acc[i][j]);

    __builtin_amdgcn_sched_barrier(0);
    __builtin_amdgcn_s_barrier();
    cur ^= 1;
  }

  const int lr = lane & 15;
  if (EPI == 3 && (n0 % 192) >= 128) {
    // v col-block: write transposed into vT[bh][d][s], 4 rows packed per 8B store
    const int hh = n0 / 192;
#pragma unroll
    for (int j = 0; j < NJ; ++j) {
      int col = n0 + wn * (NJ * 16) + j * 16 + lr;
      int d = (col % 192) - 128;
      float bcol = bias[col];
#pragma unroll
      for (int i = 0; i < MI; ++i) {
        int rowb = m0 + wm * (MI * 16) + i * 16 + (lane >> 4) * 4;
        int bb_ = rowb >> 9, s0 = rowb & 511;
        unsigned short u[4];
#pragma unroll
        for (int r = 0; r < 4; ++r) {
          hbf t = __float2bfloat16(acc[i][j][r] + bcol);
          u[r] = *reinterpret_cast<unsigned short*>(&t);
        }
        uint2 pk;
        pk.x = (unsigned)u[0] | ((unsigned)u[1] << 16);
        pk.y = (unsigned)u[2] | ((unsigned)u[3] << 16);
        *reinterpret_cast<uint2*>(outp2 + ((size_t)(bb_ * 8 + hh) * 64 + d) * 512 + s0) = pk;
      }
    }
    return;
  }

#pragma unroll
  for (int j = 0; j < NJ; ++j) {
    int col = n0 + wn * (NJ * 16) + j * 16 + lr;
    float bcol = bias[col];
#pragma unroll
    for (int i = 0; i < MI; ++i) {
      int rowb = m0 + wm * (MI * 16) + i * 16 + (lane >> 4) * 4;
#pragma unroll
      for (int r = 0; r < 4; ++r) {
        int row = rowb + r;
        float v = acc[i][j][r] + bcol;
        if (EPI == 0) {
          v = v > 0.f ? v : 0.f;
          ((hbf*)outp)[(size_t)row * N + col] = __float2bfloat16(v);
        } else if (EPI == 1 || EPI == 3) {
          ((hbf*)outp)[(size_t)row * N + col] = __float2bfloat16(v);
        } else {
          ((float*)outp)[(size_t)row * N + col] = v + resid[(size_t)row * N + col];
        }
      }
    }
  }
}

// ---------------- causal flash attention, fused pos-bias, static-max softmax ----------------
__global__ __launch_bounds__(256) void attn_kernel(const hbf* __restrict__ X2,
                                                   const hbf* __restrict__ vT,
                                                   const float* __restrict__ Wp,
                                                   const float* __restrict__ bp,
                                                   float* __restrict__ obuf) {
  __shared__ float bias_lds[2][64];
  __shared__ hbf p_lds[4][16][32];
  // XCD swizzle: co-locate the 8 q-tiles of one bh on one XCD (K/V L2 reuse)
  const int wid = blockIdx.y * 64 + blockIdx.x;
  const int bh = ((wid & 7) << 3) | ((wid >> 3) & 7);
  const int q0 = (wid >> 6) * 64;
  const int b = bh >> 3, h = bh & 7;
  const int tid = threadIdx.x;
  const int lane = tid & 63, w = tid >> 6;
  const int qbase = q0 + w * 16;

  // ---- per-block relative-position bias: bias_lds[c][qq] = q(q0+qq) . (Wp[c]+bp)|_h ----
  if (tid < 128) {
    int c = tid >> 6, qq = tid & 63;
    const hbf* qp = X2 + (size_t)(b * 512 + q0 + qq) * 1536 + h * 192;
    const float* wr = Wp + c * 512 + h * 64;
    const float* br = bp + h * 64;
    float s = 0.f;
#pragma unroll
    for (int d8 = 0; d8 < 8; ++d8) {
      bf16x8 qv = *reinterpret_cast<const bf16x8*>(qp + d8 * 8);
#pragma unroll
      for (int j = 0; j < 8; ++j) s += (float)qv[j] * (wr[d8 * 8 + j] + br[d8 * 8 + j]);
    }
    bias_lds[c][qq] = s;
  }

  bf16x8 qa[2];
  {
    int qrow = qbase + (lane & 15);
    const hbf* qp = X2 + (size_t)(b * 512 + qrow) * 1536 + h * 192 + (lane >> 4) * 8;
#pragma unroll
    for (int c = 0; c < 2; ++c) qa[c] = *reinterpret_cast<const bf16x8*>(qp + c * 32);
  }
  __syncthreads();

  float bias0[4], bias1[4];
#pragma unroll
  for (int r = 0; r < 4; ++r) {
    int qq = w * 16 + (lane >> 4) * 4 + r;
    bias0[r] = bias_lds[0][qq];
    bias1[r] = bias_lds[1][qq];
  }

  // Static-max softmax: scores bounded well below MAXS; normalizer cancels in o = sum(p*v)/sum(p)
  const float MAXS = 16.f;
  float lsum[4] = {0.f, 0.f, 0.f, 0.f};
  f32x4 oacc[4];
#pragma unroll
  for (int nt = 0; nt < 4; ++nt) oacc[nt] = (f32x4){0.f, 0.f, 0.f, 0.f};

  const int qhi = qbase + 15;
  const int nchunks = (qhi >> 5) + 1;
  for (int ch = 0; ch < nchunks; ++ch) {
    const int k32 = ch * 32;
    f32x4 z = {0.f, 0.f, 0.f, 0.f};
    f32x4 s0, s1;
    {
      const hbf* kp = X2 + (size_t)(b * 512 + k32 + (lane & 15)) * 1536 + h * 192 + 64 + (lane >> 4) * 8;
      bf16x8 kb = *reinterpret_cast<const bf16x8*>(kp);
      s0 = MFMA16(qa[0], kb, z);
      kb = *reinterpret_cast<const bf16x8*>(kp + 32);
      s0 = MFMA16(qa[1], kb, s0);
      const hbf* kp1 = kp + 16 * 1536;
      kb = *reinterpret_cast<const bf16x8*>(kp1);
      s1 = MFMA16(qa[0], kb, z);
      kb = *reinterpret_cast<const bf16x8*>(kp1 + 32);
      s1 = MFMA16(qa[1], kb, s1);
    }
    const int col0 = k32 + (lane & 15);
    const int col1 = col0 + 16;
#pragma unroll
    for (int r = 0; r < 4; ++r) {
      int q = qbase + (lane >> 4) * 4 + r;
      float sc0 = (col0 > q) ? -1e30f : (s0[r] * 0.125f + (col0 == q ? bias1[r] : bias0[r]));
      float sc1 = (col1 > q) ? -1e30f : (s1[r] * 0.125f + (col1 == q ? bias1[r] : bias0[r]));
      float p0 = __expf(sc0 - MAXS);
      float p1 = __expf(sc1 - MAXS);
      lsum[r] += p0 + p1;
      p_lds[w][(lane >> 4) * 4 + r][lane & 15] = __float2bfloat16(p0);
      p_lds[w][(lane >> 4) * 4 + r][16 + (lane & 15)] = __float2bfloat16(p1);
    }
    bf16x8 pa = *reinterpret_cast<const bf16x8*>(&p_lds[w][lane & 15][(lane >> 4) * 8]);
#pragma unroll
    for (int nt = 0; nt < 4; ++nt) {
      const hbf* vp = vT + ((size_t)bh * 64 + nt * 16 + (lane & 15)) * 512 + k32 + (lane >> 4) * 8;
      bf16x8 vb = *reinterpret_cast<const bf16x8*>(vp);
      oacc[nt] = MFMA16(pa, vb, oacc[nt]);
    }
  }
#pragma unroll
  for (int r = 0; r < 4; ++r) {
#pragma unroll
    for (int off = 1; off < 16; off <<= 1) lsum[r] += __shfl_xor(lsum[r], off);
    float rl = 1.f / lsum[r];
    int q = qbase + (lane >> 4) * 4 + r;
    float* orow = obuf + (size_t)(b * 512 + q) * 512 + h * 64;
#pragma unroll
    for (int nt = 0; nt < 4; ++nt) orow[nt * 16 + (lane & 15)] = oacc[nt][r] * rl;
  }
}

extern "C" void kernel_launch(void* const* d_in, const int* in_sizes, int n_in,
                              void* d_out, int out_size, void* d_ws, size_t ws_size,
                              hipStream_t stream) {
  const float* values = (const float*)d_in[0];
  const float* ln0_g = (const float*)d_in[2];
  const float* ln0_b = (const float*)d_in[3];
  const float* W0a = (const float*)d_in[4];
  const float* b0a = (const float*)d_in[5];
  const float* W0b = (const float*)d_in[6];
  const float* b0b = (const float*)d_in[7];
  const float* Wp = (const float*)d_in[8];
  const float* bp = (const float*)d_in[9];
  const float* ln1_g = (const float*)d_in[10];
  const float* ln1_b = (const float*)d_in[11];
  const float* W1a = (const float*)d_in[12];
  const float* b1a = (const float*)d_in[13];
  const float* W1b = (const float*)d_in[14];
  const float* b1b = (const float*)d_in[15];

  char* ws = (char*)d_ws;
  hbf* W0a_t = (hbf*)(ws + (0ull << 20));
  hbf* W0b_t = (hbf*)(ws + (2ull << 20));
  hbf* W1a_t = (hbf*)(ws + (8ull << 20));
  hbf* W1b_t = (hbf*)(ws + (10ull << 20));
  hbf* hbuf = (hbf*)(ws + (12ull << 20));   // LN0 out, reused as h2
  hbf* X1 = (hbf*)(ws + (16ull << 20));     // 16MB, reused as X3
  hbf* X2 = (hbf*)(ws + (32ull << 20));     // 12MB (QKV; v cols unused)
  float* obuf = (float*)(ws + (44ull << 20));  // 8MB
  hbf* vT = (hbf*)(ws + (52ull << 20));     // 4MB
  float* res1 = (float*)(ws + (57ull << 20));  // 8MB
  hbf* X3 = X1;
  hbf* h2 = hbuf;

  prep_kernel<<<2560, 256, 0, stream>>>(W0a, W0b, W1a, W1b, W0a_t, W0b_t, W1a_t, W1b_t,
                                        values, ln0_g, ln0_b, hbuf);

  gemm_bt<0, 64><<<dim3(32, 32), 256, 0, stream>>>(hbuf, W0a_t, b0a, nullptr, X1, nullptr, 4096, 2048, 512);
  gemm_bt<3, 64><<<dim3(24, 32), 256, 0, stream>>>(X1, W0b_t, b0b, nullptr, X2, vT, 4096, 1536, 2048);

  attn_kernel<<<dim3(64, 8), 256, 0, stream>>>(X2, vT, Wp, bp, obuf);

  lnadd_kernel<<<1024, 256, 0, stream>>>(values, obuf, ln1_g, ln1_b, res1, h2);

  gemm_bt<0, 64><<<dim3(32, 32), 256, 0, stream>>>(h2, W1a_t, b1a, nullptr, X3, nullptr, 4096, 2048, 512);
  gemm_bt<2, 32><<<dim3(16, 32), 256, 0, stream>>>(X3, W1b_t, b1b, res1, (float*)d_out, nullptr, 4096, 512, 2048);
}